// Round 1
// baseline (4851.778 us; speedup 1.0000x reference)
//
#include <hip/hip_runtime.h>
#include <hip/hip_bf16.h>
#include <math.h>

// Problem constants
#define B 4
#define L 2048
#define HID 896
#define NH 14
#define NKV 2
#define HD 64
#define GROUPS 7          // NH / NKV
#define QCOLS (NH * HD)   // 896
#define KCOLS (NKV * HD)  // 128
#define ROWS (B * L)      // 8192

// ---------------------------------------------------------------------------
// GEMM: C[M,N] = A[M,K] @ W[N,K]^T + bias[N]   (all fp32, M,N multiples of 64,
// K multiple of 16). 64x64 tile, 256 threads, 4x4 micro-tile per thread.
// ---------------------------------------------------------------------------
#define TILE 64
#define KT 16

__global__ __launch_bounds__(256) void gemm_bias_kernel(
    const float* __restrict__ A, const float* __restrict__ W,
    const float* __restrict__ bias, float* __restrict__ C,
    int M, int N, int K) {
  __shared__ float As[KT][TILE];
  __shared__ float Ws[KT][TILE];

  const int tid = threadIdx.x;
  const int tx = tid & 15;        // 0..15 -> n groups of 4
  const int ty = tid >> 4;        // 0..15 -> m groups of 4
  const int m0 = blockIdx.y * TILE;
  const int n0 = blockIdx.x * TILE;

  float c[4][4] = {};

  for (int k0 = 0; k0 < K; k0 += KT) {
#pragma unroll
    for (int i = 0; i < 4; ++i) {
      int idx = tid + i * 256;          // 0..1023
      int mm = idx >> 4;                // 0..63
      int kk = idx & 15;                // 0..15
      As[kk][mm] = A[(size_t)(m0 + mm) * K + k0 + kk];
      Ws[kk][mm] = W[(size_t)(n0 + mm) * K + k0 + kk];
    }
    __syncthreads();
#pragma unroll
    for (int kk = 0; kk < KT; ++kk) {
      float a[4], w[4];
#pragma unroll
      for (int i = 0; i < 4; ++i) a[i] = As[kk][ty * 4 + i];
#pragma unroll
      for (int j = 0; j < 4; ++j) w[j] = Ws[kk][tx * 4 + j];
#pragma unroll
      for (int i = 0; i < 4; ++i)
#pragma unroll
        for (int j = 0; j < 4; ++j) c[i][j] += a[i] * w[j];
    }
    __syncthreads();
  }

#pragma unroll
  for (int i = 0; i < 4; ++i) {
    int row = m0 + ty * 4 + i;
#pragma unroll
    for (int j = 0; j < 4; ++j) {
      int col = n0 + tx * 4 + j;
      float r = c[i][j];
      if (bias) r += bias[col];
      C[(size_t)row * N + col] = r;
    }
  }
}

// ---------------------------------------------------------------------------
// RoPE in-place on a [ROWS, nh*64] buffer. One thread per (row, head, d<32)
// pair. cos/sin are [L, 64] with the two halves identical (concat of freqs).
// ---------------------------------------------------------------------------
__global__ void rope_kernel(float* __restrict__ p,
                            const float* __restrict__ cosp,
                            const float* __restrict__ sinp, int nh, int total) {
  int idx = blockIdx.x * blockDim.x + threadIdx.x;
  if (idx >= total) return;
  int d = idx & 31;
  int tmp = idx >> 5;
  int hh = tmp % nh;
  int row = tmp / nh;
  int l = row & (L - 1);

  float* base = p + (size_t)row * nh * HD + hh * HD;
  float a = base[d];
  float b = base[d + 32];
  float cv = cosp[l * HD + d];
  float sv = sinp[l * HD + d];
  base[d] = a * cv - b * sv;       // q[d]*cos + (-q[d+32])*sin
  base[d + 32] = b * cv + a * sv;  // q[d+32]*cos + q[d]*sin
}

// ---------------------------------------------------------------------------
// Flash-style causal attention. One wave (64 threads) per (b, h, qi).
// Lane j scores key (j0+j); lane d accumulates output dim d.
// ---------------------------------------------------------------------------
__global__ __launch_bounds__(64) void attn_kernel(
    const float* __restrict__ q, const float* __restrict__ k,
    const float* __restrict__ v, float* __restrict__ ctx) {
  const int qi = blockIdx.x;
  const int h = blockIdx.y;
  const int b = blockIdx.z;
  const int lane = threadIdx.x;
  const int kvh = h / GROUPS;

  __shared__ float qsh[HD];
  __shared__ float psh[HD];

  const float* qrow = q + (size_t)(b * L + qi) * QCOLS + h * HD;
  qsh[lane] = qrow[lane] * 0.125f;  // fold 1/sqrt(64) into q
  __syncthreads();

  float m = -INFINITY;
  float l_sum = 0.f;
  float o = 0.f;

  for (int j0 = 0; j0 <= qi; j0 += 64) {
    const int j = j0 + lane;
    float s = -INFINITY;
    if (j <= qi) {
      const float4* krow =
          (const float4*)(k + (size_t)(b * L + j) * KCOLS + kvh * HD);
      const float4* q4 = (const float4*)qsh;
      float acc = 0.f;
#pragma unroll
      for (int d4 = 0; d4 < HD / 4; ++d4) {
        float4 kk = krow[d4];
        float4 qq = q4[d4];
        acc += kk.x * qq.x + kk.y * qq.y + kk.z * qq.z + kk.w * qq.w;
      }
      s = acc;
    }
    // wave-wide max over 64 lanes
    float mt = s;
#pragma unroll
    for (int off = 32; off >= 1; off >>= 1)
      mt = fmaxf(mt, __shfl_xor(mt, off));
    const float mnew = fmaxf(m, mt);

    const float p = __expf(s - mnew);  // s==-inf -> 0
    const float alpha = __expf(m - mnew);

    float psum = p;
#pragma unroll
    for (int off = 32; off >= 1; off >>= 1) psum += __shfl_xor(psum, off);

    psh[lane] = p;
    l_sum = l_sum * alpha + psum;
    o *= alpha;
    __syncthreads();  // psh visible

    const float* vbase = v + (size_t)(b * L + j0) * KCOLS + kvh * HD + lane;
    const int jmax = min(64, qi - j0 + 1);
    for (int jj = 0; jj < jmax; ++jj) {
      o += psh[jj] * vbase[(size_t)jj * KCOLS];
    }
    m = mnew;
    __syncthreads();  // before psh is overwritten next iter
  }

  ctx[(size_t)(b * L + qi) * QCOLS + h * HD + lane] = o / l_sum;
}

// ---------------------------------------------------------------------------
extern "C" void kernel_launch(void* const* d_in, const int* in_sizes, int n_in,
                              void* d_out, int out_size, void* d_ws,
                              size_t ws_size, hipStream_t stream) {
  const float* x = (const float*)d_in[0];
  const float* cosp = (const float*)d_in[1];
  const float* sinp = (const float*)d_in[2];
  // d_in[3] = mask (unused; causal handled analytically)
  const float* wq = (const float*)d_in[4];
  const float* bq = (const float*)d_in[5];
  const float* wk = (const float*)d_in[6];
  const float* bk = (const float*)d_in[7];
  const float* wv = (const float*)d_in[8];
  const float* bv = (const float*)d_in[9];
  const float* wo = (const float*)d_in[10];
  float* out = (float*)d_out;

  float* ws = (float*)d_ws;
  float* qbuf = ws;                       // ROWS*QCOLS = 7,340,032
  float* kbuf = qbuf + (size_t)ROWS * QCOLS;  // ROWS*KCOLS = 1,048,576
  float* vbuf = kbuf + (size_t)ROWS * KCOLS;
  float* ctx = vbuf + (size_t)ROWS * KCOLS;   // ROWS*QCOLS

  // QKV projections
  gemm_bias_kernel<<<dim3(QCOLS / TILE, ROWS / TILE), 256, 0, stream>>>(
      x, wq, bq, qbuf, ROWS, QCOLS, HID);
  gemm_bias_kernel<<<dim3(KCOLS / TILE, ROWS / TILE), 256, 0, stream>>>(
      x, wk, bk, kbuf, ROWS, KCOLS, HID);
  gemm_bias_kernel<<<dim3(KCOLS / TILE, ROWS / TILE), 256, 0, stream>>>(
      x, wv, bv, vbuf, ROWS, KCOLS, HID);

  // RoPE on q and k
  {
    int total_q = ROWS * NH * 32;
    rope_kernel<<<(total_q + 255) / 256, 256, 0, stream>>>(qbuf, cosp, sinp,
                                                           NH, total_q);
    int total_k = ROWS * NKV * 32;
    rope_kernel<<<(total_k + 255) / 256, 256, 0, stream>>>(kbuf, cosp, sinp,
                                                           NKV, total_k);
  }

  // Attention
  attn_kernel<<<dim3(L, NH, B), 64, 0, stream>>>(qbuf, kbuf, vbuf, ctx);

  // Output projection (no bias)
  gemm_bias_kernel<<<dim3(HID / TILE, ROWS / TILE), 256, 0, stream>>>(
      ctx, wo, nullptr, out, ROWS, HID, QCOLS);
}

// Round 2
// 1192.160 us; speedup vs baseline: 4.0697x; 4.0697x over previous
//
#include <hip/hip_runtime.h>
#include <hip/hip_bf16.h>
#include <math.h>

// Problem constants
#define B 4
#define L 2048
#define HID 896
#define NH 14
#define NKV 2
#define HD 64
#define GROUPS 7          // NH / NKV
#define QCOLS (NH * HD)   // 896
#define KCOLS (NKV * HD)  // 128
#define ROWS (B * L)      // 8192

typedef __attribute__((ext_vector_type(8))) short bf16x8;
typedef __attribute__((ext_vector_type(4))) float f32x4;

__device__ inline short f2bf(float f) {
  union { __hip_bfloat16 h; short s; } u;
  u.h = __float2bfloat16(f);
  return u.s;
}

// ---------------------------------------------------------------------------
// GEMM: C[M,N] = A[M,K] @ W[N,K]^T + bias[N]  (fp32, 64x64 tile, 4x4 micro)
// ---------------------------------------------------------------------------
#define TILE 64
#define KT 16

__global__ __launch_bounds__(256) void gemm_bias_kernel(
    const float* __restrict__ A, const float* __restrict__ W,
    const float* __restrict__ bias, float* __restrict__ C,
    int M, int N, int K) {
  __shared__ float As[KT][TILE];
  __shared__ float Ws[KT][TILE];

  const int tid = threadIdx.x;
  const int tx = tid & 15;
  const int ty = tid >> 4;
  const int m0 = blockIdx.y * TILE;
  const int n0 = blockIdx.x * TILE;

  float c[4][4] = {};

  for (int k0 = 0; k0 < K; k0 += KT) {
#pragma unroll
    for (int i = 0; i < 4; ++i) {
      int idx = tid + i * 256;
      int mm = idx >> 4;
      int kk = idx & 15;
      As[kk][mm] = A[(size_t)(m0 + mm) * K + k0 + kk];
      Ws[kk][mm] = W[(size_t)(n0 + mm) * K + k0 + kk];
    }
    __syncthreads();
#pragma unroll
    for (int kk = 0; kk < KT; ++kk) {
      float a[4], w[4];
#pragma unroll
      for (int i = 0; i < 4; ++i) a[i] = As[kk][ty * 4 + i];
#pragma unroll
      for (int j = 0; j < 4; ++j) w[j] = Ws[kk][tx * 4 + j];
#pragma unroll
      for (int i = 0; i < 4; ++i)
#pragma unroll
        for (int j = 0; j < 4; ++j) c[i][j] += a[i] * w[j];
    }
    __syncthreads();
  }

#pragma unroll
  for (int i = 0; i < 4; ++i) {
    int row = m0 + ty * 4 + i;
#pragma unroll
    for (int j = 0; j < 4; ++j) {
      int col = n0 + tx * 4 + j;
      float r = c[i][j];
      if (bias) r += bias[col];
      C[(size_t)row * N + col] = r;
    }
  }
}

// ---------------------------------------------------------------------------
// RoPE in-place on a [ROWS, nh*64] buffer.
// ---------------------------------------------------------------------------
__global__ void rope_kernel(float* __restrict__ p,
                            const float* __restrict__ cosp,
                            const float* __restrict__ sinp, int nh, int total) {
  int idx = blockIdx.x * blockDim.x + threadIdx.x;
  if (idx >= total) return;
  int d = idx & 31;
  int tmp = idx >> 5;
  int hh = tmp % nh;
  int row = tmp / nh;
  int l = row & (L - 1);

  float* base = p + (size_t)row * nh * HD + hh * HD;
  float a = base[d];
  float b = base[d + 32];
  float cv = cosp[l * HD + d];
  float sv = sinp[l * HD + d];
  base[d] = a * cv - b * sv;
  base[d + 32] = b * cv + a * sv;
}

// ---------------------------------------------------------------------------
// Flash attention with bf16 MFMA. Block = 4 waves; wave w owns Q rows
// [qb + 16w, qb + 16w + 16). Loop over 32-key tiles staged in LDS.
//
// mfma_f32_16x16x32_bf16 layouts (verified on gfx950):
//   A[m = lane&15][k = (lane>>4)*8 + j]   (8 bf16 / lane)
//   B[k = (lane>>4)*8 + j][n = lane&15]
//   C/D: col = lane&15, row = (lane>>4)*4 + reg
// ---------------------------------------------------------------------------
#define BQ 64   // q rows per block
#define QT 16   // q rows per wave
#define BK 32   // keys per iteration

// LDS row strides (bf16 elements) padded so ds_read_b128 is <=2-way conflict
#define KSTR 72  // K tile: [32 keys][64 d]
#define VSTR 40  // V tile (transposed): [64 d][32 keys]
#define PSTR 40  // P tile per wave: [16 q][32 keys]

__global__ __launch_bounds__(256) void attn_mfma_kernel(
    const float* __restrict__ q, const float* __restrict__ k,
    const float* __restrict__ v, float* __restrict__ ctx) {
  const int qb = blockIdx.x * BQ;
  const int h = blockIdx.y;
  const int b = blockIdx.z;
  const int kvh = h / GROUPS;
  const int tid = threadIdx.x;
  const int wave = tid >> 6;
  const int lane = tid & 63;
  const int l15 = lane & 15;
  const int quad = lane >> 4;

  __shared__ short Kt[32 * KSTR];
  __shared__ short Vt[64 * VSTR];
  __shared__ short Pt[4 * 16 * PSTR];

  const int qrow_base = qb + wave * QT;
  const int wave_qmax = qrow_base + QT - 1;

  // Q A-fragments for d-halves [0,32) and [32,64), scale 1/sqrt(64) folded in
  bf16x8 qfrag[2];
  {
    const float* qp =
        q + (size_t)(b * L + qrow_base + l15) * QCOLS + h * HD;
#pragma unroll
    for (int half = 0; half < 2; ++half) {
      short tmp[8];
#pragma unroll
      for (int j = 0; j < 8; ++j)
        tmp[j] = f2bf(qp[half * 32 + quad * 8 + j] * 0.125f);
      qfrag[half] = *(bf16x8*)tmp;
    }
  }

  float mrow[4] = {-INFINITY, -INFINITY, -INFINITY, -INFINITY};
  float lrow[4] = {0.f, 0.f, 0.f, 0.f};
  f32x4 oacc[4] = {};  // [d-chunk][reg]: D[row=quad*4+reg][col=chunk*16+l15]

  const float* kbase = k + (size_t)(b * L) * KCOLS + kvh * HD;
  const float* vbase = v + (size_t)(b * L) * KCOLS + kvh * HD;

  const int kend = qb + BQ;
  for (int j0 = 0; j0 < kend; j0 += BK) {
    __syncthreads();  // previous tile fully consumed
    // ---- stage K and V^T (fp32 -> bf16) ----
    {
      const int d4 = tid & 15;   // float4 index along d
      const int key0 = tid >> 4; // 0..15
#pragma unroll
      for (int kk = key0; kk < BK; kk += 16) {
        float4 k4 = *(const float4*)(kbase + (size_t)(j0 + kk) * KCOLS + d4 * 4);
        short4 s4;
        s4.x = f2bf(k4.x); s4.y = f2bf(k4.y);
        s4.z = f2bf(k4.z); s4.w = f2bf(k4.w);
        *(short4*)(&Kt[kk * KSTR + d4 * 4]) = s4;
        float4 v4 = *(const float4*)(vbase + (size_t)(j0 + kk) * KCOLS + d4 * 4);
        Vt[(d4 * 4 + 0) * VSTR + kk] = f2bf(v4.x);
        Vt[(d4 * 4 + 1) * VSTR + kk] = f2bf(v4.y);
        Vt[(d4 * 4 + 2) * VSTR + kk] = f2bf(v4.z);
        Vt[(d4 * 4 + 3) * VSTR + kk] = f2bf(v4.w);
      }
    }
    __syncthreads();

    if (j0 > wave_qmax) continue;  // wave-uniform; keeps barrier counts equal

    // ---- S = Q K^T over two 16-key subtiles ----
    f32x4 S[2];
#pragma unroll
    for (int t = 0; t < 2; ++t) {
      bf16x8 b0 = *(bf16x8*)(&Kt[(t * 16 + l15) * KSTR + quad * 8]);
      bf16x8 b1 = *(bf16x8*)(&Kt[(t * 16 + l15) * KSTR + 32 + quad * 8]);
      f32x4 acc = {};
      acc = __builtin_amdgcn_mfma_f32_16x16x32_bf16(qfrag[0], b0, acc, 0, 0, 0);
      acc = __builtin_amdgcn_mfma_f32_16x16x32_bf16(qfrag[1], b1, acc, 0, 0, 0);
      S[t] = acc;
    }

    // ---- causal mask + online softmax (row = qrow_base + quad*4 + r) ----
    float p0v[4], p1v[4], alpha[4];
#pragma unroll
    for (int r = 0; r < 4; ++r) {
      const int qrow = qrow_base + quad * 4 + r;
      float s0 = (j0 + l15 <= qrow) ? S[0][r] : -INFINITY;
      float s1 = (j0 + 16 + l15 <= qrow) ? S[1][r] : -INFINITY;
      float mt = fmaxf(s0, s1);
      mt = fmaxf(mt, __shfl_xor(mt, 1));
      mt = fmaxf(mt, __shfl_xor(mt, 2));
      mt = fmaxf(mt, __shfl_xor(mt, 4));
      mt = fmaxf(mt, __shfl_xor(mt, 8));
      const float mn = fmaxf(mrow[r], mt);
      const float p0 = __expf(s0 - mn);
      const float p1 = __expf(s1 - mn);
      float ps = p0 + p1;
      ps += __shfl_xor(ps, 1);
      ps += __shfl_xor(ps, 2);
      ps += __shfl_xor(ps, 4);
      ps += __shfl_xor(ps, 8);
      const float al = __expf(mrow[r] - mn);
      lrow[r] = lrow[r] * al + ps;
      mrow[r] = mn;
      alpha[r] = al;
      p0v[r] = p0;
      p1v[r] = p1;
    }

    // ---- P -> LDS (C-layout write), then A-layout read ----
    short* Pw = &Pt[wave * 16 * PSTR];
#pragma unroll
    for (int r = 0; r < 4; ++r) {
      Pw[(quad * 4 + r) * PSTR + l15] = f2bf(p0v[r]);
      Pw[(quad * 4 + r) * PSTR + 16 + l15] = f2bf(p1v[r]);
    }
#pragma unroll
    for (int c = 0; c < 4; ++c)
#pragma unroll
      for (int r = 0; r < 4; ++r) oacc[c][r] *= alpha[r];

    bf16x8 pfrag = *(bf16x8*)(&Pw[l15 * PSTR + quad * 8]);

    // ---- O += P V ----
#pragma unroll
    for (int c = 0; c < 4; ++c) {
      bf16x8 vfrag = *(bf16x8*)(&Vt[(c * 16 + l15) * VSTR + quad * 8]);
      oacc[c] = __builtin_amdgcn_mfma_f32_16x16x32_bf16(pfrag, vfrag, oacc[c],
                                                        0, 0, 0);
    }
  }

  // ---- epilogue ----
  float* cp = ctx + (size_t)(b * L) * QCOLS + h * HD;
#pragma unroll
  for (int r = 0; r < 4; ++r) {
    const int qrow = qrow_base + quad * 4 + r;
    const float inv = 1.0f / lrow[r];
#pragma unroll
    for (int c = 0; c < 4; ++c)
      cp[(size_t)qrow * QCOLS + c * 16 + l15] = oacc[c][r] * inv;
  }
}

// ---------------------------------------------------------------------------
extern "C" void kernel_launch(void* const* d_in, const int* in_sizes, int n_in,
                              void* d_out, int out_size, void* d_ws,
                              size_t ws_size, hipStream_t stream) {
  const float* x = (const float*)d_in[0];
  const float* cosp = (const float*)d_in[1];
  const float* sinp = (const float*)d_in[2];
  // d_in[3] = mask (unused; causal handled analytically)
  const float* wq = (const float*)d_in[4];
  const float* bq = (const float*)d_in[5];
  const float* wk = (const float*)d_in[6];
  const float* bk = (const float*)d_in[7];
  const float* wv = (const float*)d_in[8];
  const float* bv = (const float*)d_in[9];
  const float* wo = (const float*)d_in[10];
  float* out = (float*)d_out;

  float* ws = (float*)d_ws;
  float* qbuf = ws;
  float* kbuf = qbuf + (size_t)ROWS * QCOLS;
  float* vbuf = kbuf + (size_t)ROWS * KCOLS;
  float* ctx = vbuf + (size_t)ROWS * KCOLS;

  gemm_bias_kernel<<<dim3(QCOLS / TILE, ROWS / TILE), 256, 0, stream>>>(
      x, wq, bq, qbuf, ROWS, QCOLS, HID);
  gemm_bias_kernel<<<dim3(KCOLS / TILE, ROWS / TILE), 256, 0, stream>>>(
      x, wk, bk, kbuf, ROWS, KCOLS, HID);
  gemm_bias_kernel<<<dim3(KCOLS / TILE, ROWS / TILE), 256, 0, stream>>>(
      x, wv, bv, vbuf, ROWS, KCOLS, HID);

  {
    int total_q = ROWS * NH * 32;
    rope_kernel<<<(total_q + 255) / 256, 256, 0, stream>>>(qbuf, cosp, sinp,
                                                           NH, total_q);
    int total_k = ROWS * NKV * 32;
    rope_kernel<<<(total_k + 255) / 256, 256, 0, stream>>>(kbuf, cosp, sinp,
                                                           NKV, total_k);
  }

  attn_mfma_kernel<<<dim3(L / BQ, NH, B), 256, 0, stream>>>(qbuf, kbuf, vbuf,
                                                            ctx);

  gemm_bias_kernel<<<dim3(HID / TILE, ROWS / TILE), 256, 0, stream>>>(
      ctx, wo, nullptr, out, ROWS, HID, QCOLS);
}

// Round 3
// 633.635 us; speedup vs baseline: 7.6571x; 1.8815x over previous
//
#include <hip/hip_runtime.h>
#include <hip/hip_bf16.h>
#include <math.h>

// Problem constants
#define B 4
#define L 2048
#define HID 896
#define NH 14
#define NKV 2
#define HD 64
#define GROUPS 7           // NH / NKV
#define QCOLS (NH * HD)    // 896
#define KCOLS (NKV * HD)   // 128
#define ROWS (B * L)       // 8192
#define QKVS 1152          // fused qkv row stride (896 q + 128 k + 128 v)

typedef __attribute__((ext_vector_type(8))) short bf16x8;
typedef __attribute__((ext_vector_type(4))) float f32x4;

__device__ inline short f2bf(float f) {
  union { __hip_bfloat16 h; short s; } u;
  u.h = __float2bfloat16(f);
  return u.s;
}

__device__ inline void gload_lds16(const void* g, void* l) {
  __builtin_amdgcn_global_load_lds(
      (const __attribute__((address_space(1))) unsigned int*)g,
      (__attribute__((address_space(3))) unsigned int*)l, 16, 0, 0);
}

// ---------------------------------------------------------------------------
// fp32 -> bf16 cast, 8 elements / thread (n must be divisible by 8)
// ---------------------------------------------------------------------------
__global__ void cast_bf16_kernel(const float* __restrict__ in,
                                 short* __restrict__ out, int n8) {
  int i = blockIdx.x * blockDim.x + threadIdx.x;
  if (i >= n8) return;
  const float4* p = (const float4*)in + (size_t)i * 2;
  float4 a = p[0], b = p[1];
  short s[8];
  s[0] = f2bf(a.x); s[1] = f2bf(a.y); s[2] = f2bf(a.z); s[3] = f2bf(a.w);
  s[4] = f2bf(b.x); s[5] = f2bf(b.y); s[6] = f2bf(b.z); s[7] = f2bf(b.w);
  *(bf16x8*)(out + (size_t)i * 8) = *(bf16x8*)s;
}

// pack bq|bk|bv into one [1152] fp32 vector
__global__ void pack_bias_kernel(const float* __restrict__ bq,
                                 const float* __restrict__ bk,
                                 const float* __restrict__ bv,
                                 float* __restrict__ o) {
  int i = blockIdx.x * blockDim.x + threadIdx.x;
  if (i >= QKVS) return;
  float v;
  if (i < QCOLS) v = bq[i];
  else if (i < QCOLS + KCOLS) v = bk[i - QCOLS];
  else v = bv[i - QCOLS - KCOLS];
  o[i] = v;
}

// ---------------------------------------------------------------------------
// bf16 MFMA GEMM: C[M,N] = A[M,K] @ W[N,K]^T (+ bias), fp32 out.
// 128x128 tile, BK=32, 4 waves in 2x2, global_load_lds staging (m97 style).
// M,N multiples of 128, K multiple of 32.
// ---------------------------------------------------------------------------
#define GTM 128
#define GTN 128
#define GTK 32

__global__ __launch_bounds__(256) void gemm_bf16_kernel(
    const short* __restrict__ A, const short* __restrict__ W,
    const float* __restrict__ bias, float* __restrict__ C,
    int M, int N, int K) {
  __shared__ short As[GTM * GTK];
  __shared__ short Bs[GTN * GTK];

  const int tid = threadIdx.x;
  const int wave = tid >> 6;
  const int lane = tid & 63;
  const int l15 = lane & 15;
  const int quad = lane >> 4;
  const int m0 = blockIdx.y * GTM;
  const int n0 = blockIdx.x * GTN;
  const int wm = (wave >> 1) * 64;
  const int wn = (wave & 1) * 64;

  f32x4 acc[4][4] = {};

  const int c0 = tid, c1 = tid + 256;
  const int r0 = c0 >> 2, ko0 = (c0 & 3) * 8;
  const int r1 = c1 >> 2, ko1 = (c1 & 3) * 8;
  const short* Ag0 = A + (size_t)(m0 + r0) * K + ko0;
  const short* Ag1 = A + (size_t)(m0 + r1) * K + ko1;
  const short* Wg0 = W + (size_t)(n0 + r0) * K + ko0;
  const short* Wg1 = W + (size_t)(n0 + r1) * K + ko1;

  for (int k0 = 0; k0 < K; k0 += GTK) {
    __syncthreads();
    gload_lds16(Ag0 + k0, As + c0 * 8);
    gload_lds16(Ag1 + k0, As + c1 * 8);
    gload_lds16(Wg0 + k0, Bs + c0 * 8);
    gload_lds16(Wg1 + k0, Bs + c1 * 8);
    __syncthreads();

    bf16x8 af[4], bf[4];
#pragma unroll
    for (int i = 0; i < 4; ++i)
      af[i] = *(bf16x8*)(As + (wm + i * 16 + l15) * GTK + quad * 8);
#pragma unroll
    for (int j = 0; j < 4; ++j)
      bf[j] = *(bf16x8*)(Bs + (wn + j * 16 + l15) * GTK + quad * 8);
#pragma unroll
    for (int i = 0; i < 4; ++i)
#pragma unroll
      for (int j = 0; j < 4; ++j)
        acc[i][j] = __builtin_amdgcn_mfma_f32_16x16x32_bf16(af[i], bf[j],
                                                            acc[i][j], 0, 0, 0);
  }

#pragma unroll
  for (int j = 0; j < 4; ++j) {
    const int col = n0 + wn + j * 16 + l15;
    const float bv = bias ? bias[col] : 0.f;
#pragma unroll
    for (int i = 0; i < 4; ++i) {
      const int rowb = m0 + wm + i * 16 + quad * 4;
#pragma unroll
      for (int r = 0; r < 4; ++r)
        C[(size_t)(rowb + r) * N + col] = acc[i][j][r] + bv;
    }
  }
}

// ---------------------------------------------------------------------------
// RoPE in-place on fused qkv buffer: base p (col offset pre-applied), row
// stride QKVS, nh heads.
// ---------------------------------------------------------------------------
__global__ void rope_kernel(float* __restrict__ p,
                            const float* __restrict__ cosp,
                            const float* __restrict__ sinp, int nh, int total) {
  int idx = blockIdx.x * blockDim.x + threadIdx.x;
  if (idx >= total) return;
  int d = idx & 31;
  int tmp = idx >> 5;
  int hh = tmp % nh;
  int row = tmp / nh;
  int l = row & (L - 1);

  float* base = p + (size_t)row * QKVS + hh * HD;
  float a = base[d];
  float b = base[d + 32];
  float cv = cosp[l * HD + d];
  float sv = sinp[l * HD + d];
  base[d] = a * cv - b * sv;
  base[d + 32] = b * cv + a * sv;
}

// ---------------------------------------------------------------------------
// Flash attention with bf16 MFMA on the fused qkv buffer; ctx out in bf16.
// Block = 4 waves; wave w owns Q rows [qb+16w, qb+16w+16). 32-key tiles.
// ---------------------------------------------------------------------------
#define BQ 64
#define QT 16
#define BK 32

#define KSTR 66  // K tile [32 keys][64 d] bf16, padded
#define VSTR 34  // V^T tile [64 d][32 keys]
#define PSTR 36  // P tile per wave [16 q][32 keys]

__global__ __launch_bounds__(256) void attn_mfma_kernel(
    const float* __restrict__ qkv, __hip_bfloat16* __restrict__ ctx) {
  const int qb = blockIdx.x * BQ;
  const int h = blockIdx.y;
  const int b = blockIdx.z;
  const int kvh = h / GROUPS;
  const int tid = threadIdx.x;
  const int wave = tid >> 6;
  const int lane = tid & 63;
  const int l15 = lane & 15;
  const int quad = lane >> 4;

  __shared__ short Kt[32 * KSTR];
  __shared__ short Vt[64 * VSTR];
  __shared__ short Pt[4 * 16 * PSTR];

  const int qrow_base = qb + wave * QT;
  const int wave_qmax = qrow_base + QT - 1;

  bf16x8 qfrag[2];
  {
    const float* qp =
        qkv + (size_t)(b * L + qrow_base + l15) * QKVS + h * HD;
#pragma unroll
    for (int half = 0; half < 2; ++half) {
      short tmp[8];
#pragma unroll
      for (int j = 0; j < 8; ++j)
        tmp[j] = f2bf(qp[half * 32 + quad * 8 + j] * 0.125f);
      qfrag[half] = *(bf16x8*)tmp;
    }
  }

  float mrow[4] = {-INFINITY, -INFINITY, -INFINITY, -INFINITY};
  float lrow[4] = {0.f, 0.f, 0.f, 0.f};
  f32x4 oacc[4] = {};

  const float* kbase = qkv + (size_t)(b * L) * QKVS + QCOLS + kvh * HD;
  const float* vbase = qkv + (size_t)(b * L) * QKVS + QCOLS + KCOLS + kvh * HD;

  const int kend = qb + BQ;
  for (int j0 = 0; j0 < kend; j0 += BK) {
    __syncthreads();
    // ---- stage K (row-major, float4 loads) ----
    {
      const int d4 = tid & 15;
      const int key0 = tid >> 4;
#pragma unroll
      for (int kk = key0; kk < BK; kk += 16) {
        float4 k4 = *(const float4*)(kbase + (size_t)(j0 + kk) * QKVS + d4 * 4);
        short4 s4;
        s4.x = f2bf(k4.x); s4.y = f2bf(k4.y);
        s4.z = f2bf(k4.z); s4.w = f2bf(k4.w);
        *(short4*)(&Kt[kk * KSTR + d4 * 4]) = s4;
      }
    }
    // ---- stage V^T: coalesced row loads, conflict-free transpose writes ----
    {
      const int d = tid & 63;
      const int kk0 = tid >> 6;  // wave-uniform
#pragma unroll
      for (int kk = kk0; kk < BK; kk += 4) {
        float vv = vbase[(size_t)(j0 + kk) * QKVS + d];
        Vt[d * VSTR + kk] = f2bf(vv);
      }
    }
    __syncthreads();

    if (j0 > wave_qmax) continue;

    // ---- S = Q K^T ----
    f32x4 S[2];
#pragma unroll
    for (int t = 0; t < 2; ++t) {
      bf16x8 b0 = *(bf16x8*)(&Kt[(t * 16 + l15) * KSTR + quad * 8]);
      bf16x8 b1 = *(bf16x8*)(&Kt[(t * 16 + l15) * KSTR + 32 + quad * 8]);
      f32x4 acc = {};
      acc = __builtin_amdgcn_mfma_f32_16x16x32_bf16(qfrag[0], b0, acc, 0, 0, 0);
      acc = __builtin_amdgcn_mfma_f32_16x16x32_bf16(qfrag[1], b1, acc, 0, 0, 0);
      S[t] = acc;
    }

    // ---- causal mask + online softmax ----
    float p0v[4], p1v[4], alpha[4];
#pragma unroll
    for (int r = 0; r < 4; ++r) {
      const int qrow = qrow_base + quad * 4 + r;
      float s0 = (j0 + l15 <= qrow) ? S[0][r] : -INFINITY;
      float s1 = (j0 + 16 + l15 <= qrow) ? S[1][r] : -INFINITY;
      float mt = fmaxf(s0, s1);
      mt = fmaxf(mt, __shfl_xor(mt, 1));
      mt = fmaxf(mt, __shfl_xor(mt, 2));
      mt = fmaxf(mt, __shfl_xor(mt, 4));
      mt = fmaxf(mt, __shfl_xor(mt, 8));
      const float mn = fmaxf(mrow[r], mt);
      const float p0 = __expf(s0 - mn);
      const float p1 = __expf(s1 - mn);
      float ps = p0 + p1;
      ps += __shfl_xor(ps, 1);
      ps += __shfl_xor(ps, 2);
      ps += __shfl_xor(ps, 4);
      ps += __shfl_xor(ps, 8);
      const float al = __expf(mrow[r] - mn);
      lrow[r] = lrow[r] * al + ps;
      mrow[r] = mn;
      alpha[r] = al;
      p0v[r] = p0;
      p1v[r] = p1;
    }

    // ---- P: C-layout write -> A-layout read ----
    short* Pw = &Pt[wave * 16 * PSTR];
#pragma unroll
    for (int r = 0; r < 4; ++r) {
      Pw[(quad * 4 + r) * PSTR + l15] = f2bf(p0v[r]);
      Pw[(quad * 4 + r) * PSTR + 16 + l15] = f2bf(p1v[r]);
    }
#pragma unroll
    for (int c = 0; c < 4; ++c)
#pragma unroll
      for (int r = 0; r < 4; ++r) oacc[c][r] *= alpha[r];

    bf16x8 pfrag = *(bf16x8*)(&Pw[l15 * PSTR + quad * 8]);

#pragma unroll
    for (int c = 0; c < 4; ++c) {
      bf16x8 vfrag = *(bf16x8*)(&Vt[(c * 16 + l15) * VSTR + quad * 8]);
      oacc[c] = __builtin_amdgcn_mfma_f32_16x16x32_bf16(pfrag, vfrag, oacc[c],
                                                        0, 0, 0);
    }
  }

  // ---- epilogue: bf16 ctx ----
  __hip_bfloat16* cp = ctx + (size_t)(b * L) * QCOLS + h * HD;
#pragma unroll
  for (int r = 0; r < 4; ++r) {
    const int qrow = qrow_base + quad * 4 + r;
    const float inv = 1.0f / lrow[r];
#pragma unroll
    for (int c = 0; c < 4; ++c)
      cp[(size_t)qrow * QCOLS + c * 16 + l15] =
          __float2bfloat16(oacc[c][r] * inv);
  }
}

// ---------------------------------------------------------------------------
extern "C" void kernel_launch(void* const* d_in, const int* in_sizes, int n_in,
                              void* d_out, int out_size, void* d_ws,
                              size_t ws_size, hipStream_t stream) {
  const float* x = (const float*)d_in[0];
  const float* cosp = (const float*)d_in[1];
  const float* sinp = (const float*)d_in[2];
  // d_in[3] = mask (unused)
  const float* wq = (const float*)d_in[4];
  const float* bq = (const float*)d_in[5];
  const float* wk = (const float*)d_in[6];
  const float* bk = (const float*)d_in[7];
  const float* wv = (const float*)d_in[8];
  const float* bv = (const float*)d_in[9];
  const float* wo = (const float*)d_in[10];
  float* out = (float*)d_out;

  // workspace layout (16B aligned chunks)
  char* ws = (char*)d_ws;
  float* qkv = (float*)ws;                       // ROWS*QKVS fp32 = 37.75 MB
  ws += (size_t)ROWS * QKVS * 4;
  short* xb = (short*)ws;                        // ROWS*HID bf16 = 14.7 MB
  ws += (size_t)ROWS * HID * 2;
  short* wqkvb = (short*)ws;                     // 1152*896 bf16 = 2.06 MB
  ws += (size_t)QKVS * HID * 2;
  short* wob = (short*)ws;                       // 896*896 bf16 = 1.6 MB
  ws += (size_t)HID * QCOLS * 2;
  short* ctxb = (short*)ws;                      // ROWS*896 bf16 = 14.7 MB
  ws += (size_t)ROWS * QCOLS * 2;
  float* bqkv = (float*)ws;                      // 1152 fp32
  ws += QKVS * 4;

  // casts / packing
  {
    int n8 = ROWS * HID / 8;
    cast_bf16_kernel<<<(n8 + 255) / 256, 256, 0, stream>>>(x, xb, n8);
    int nq8 = QCOLS * HID / 8;
    cast_bf16_kernel<<<(nq8 + 255) / 256, 256, 0, stream>>>(wq, wqkvb, nq8);
    int nk8 = KCOLS * HID / 8;
    cast_bf16_kernel<<<(nk8 + 255) / 256, 256, 0, stream>>>(
        wk, wqkvb + (size_t)QCOLS * HID, nk8);
    cast_bf16_kernel<<<(nk8 + 255) / 256, 256, 0, stream>>>(
        wv, wqkvb + (size_t)(QCOLS + KCOLS) * HID, nk8);
    int no8 = HID * QCOLS / 8;
    cast_bf16_kernel<<<(no8 + 255) / 256, 256, 0, stream>>>(wo, wob, no8);
    pack_bias_kernel<<<(QKVS + 255) / 256, 256, 0, stream>>>(bq, bk, bv, bqkv);
  }

  // fused QKV projection: [8192,1152] = xb @ wqkvb^T + bqkv
  gemm_bf16_kernel<<<dim3(QKVS / GTN, ROWS / GTM), 256, 0, stream>>>(
      xb, wqkvb, bqkv, qkv, ROWS, QKVS, HID);

  // RoPE on q and k parts of qkv
  {
    int total_q = ROWS * NH * 32;
    rope_kernel<<<(total_q + 255) / 256, 256, 0, stream>>>(qkv, cosp, sinp, NH,
                                                           total_q);
    int total_k = ROWS * NKV * 32;
    rope_kernel<<<(total_k + 255) / 256, 256, 0, stream>>>(qkv + QCOLS, cosp,
                                                           sinp, NKV, total_k);
  }

  // attention -> bf16 ctx
  attn_mfma_kernel<<<dim3(L / BQ, NH, B), 256, 0, stream>>>(qkv, (__hip_bfloat16*)ctxb);

  // output projection: out = ctxb @ wob^T
  gemm_bf16_kernel<<<dim3(HID / GTN, ROWS / GTM), 256, 0, stream>>>(
      ctxb, wob, nullptr, out, ROWS, HID, QCOLS);
}

// Round 4
// 512.793 us; speedup vs baseline: 9.4615x; 1.2357x over previous
//
#include <hip/hip_runtime.h>
#include <hip/hip_bf16.h>
#include <math.h>

// Problem constants
#define B 4
#define L 2048
#define HID 896
#define NH 14
#define NKV 2
#define HD 64
#define GROUPS 7           // NH / NKV
#define QCOLS (NH * HD)    // 896
#define KCOLS (NKV * HD)   // 128
#define ROWS (B * L)       // 8192
#define QKVS 1152          // fused qkv row stride (896 q + 128 k + 128 v)

typedef __attribute__((ext_vector_type(8))) short bf16x8;
typedef __attribute__((ext_vector_type(4))) float f32x4;

__device__ inline short f2bf(float f) {
  union { __hip_bfloat16 h; short s; } u;
  u.h = __float2bfloat16(f);
  return u.s;
}

__device__ inline void gload_lds16(const void* g, void* l) {
  __builtin_amdgcn_global_load_lds(
      (const __attribute__((address_space(1))) unsigned int*)g,
      (__attribute__((address_space(3))) unsigned int*)l, 16, 0, 0);
}

// 16-lane (row) all-reduce via DPP — VALU only, no DS pipe.
__device__ inline float row_max16(float x) {
  x = fmaxf(x, __int_as_float(__builtin_amdgcn_mov_dpp(
                   __float_as_int(x), 0xB1, 0xF, 0xF, true)));  // xor 1
  x = fmaxf(x, __int_as_float(__builtin_amdgcn_mov_dpp(
                   __float_as_int(x), 0x4E, 0xF, 0xF, true)));  // xor 2
  x = fmaxf(x, __int_as_float(__builtin_amdgcn_mov_dpp(
                   __float_as_int(x), 0x141, 0xF, 0xF, true))); // half-mirror
  x = fmaxf(x, __int_as_float(__builtin_amdgcn_mov_dpp(
                   __float_as_int(x), 0x140, 0xF, 0xF, true))); // mirror
  return x;
}
__device__ inline float row_sum16(float x) {
  x += __int_as_float(__builtin_amdgcn_mov_dpp(
      __float_as_int(x), 0xB1, 0xF, 0xF, true));
  x += __int_as_float(__builtin_amdgcn_mov_dpp(
      __float_as_int(x), 0x4E, 0xF, 0xF, true));
  x += __int_as_float(__builtin_amdgcn_mov_dpp(
      __float_as_int(x), 0x141, 0xF, 0xF, true));
  x += __int_as_float(__builtin_amdgcn_mov_dpp(
      __float_as_int(x), 0x140, 0xF, 0xF, true));
  return x;
}

// ---------------------------------------------------------------------------
// fp32 -> bf16 cast, 8 elements / thread
// ---------------------------------------------------------------------------
__global__ void cast_bf16_kernel(const float* __restrict__ in,
                                 short* __restrict__ out, int n8) {
  int i = blockIdx.x * blockDim.x + threadIdx.x;
  if (i >= n8) return;
  const float4* p = (const float4*)in + (size_t)i * 2;
  float4 a = p[0], b = p[1];
  short s[8];
  s[0] = f2bf(a.x); s[1] = f2bf(a.y); s[2] = f2bf(a.z); s[3] = f2bf(a.w);
  s[4] = f2bf(b.x); s[5] = f2bf(b.y); s[6] = f2bf(b.z); s[7] = f2bf(b.w);
  *(bf16x8*)(out + (size_t)i * 8) = *(bf16x8*)s;
}

// pack bq|bk|bv into one [1152] fp32 vector
__global__ void pack_bias_kernel(const float* __restrict__ bq,
                                 const float* __restrict__ bk,
                                 const float* __restrict__ bv,
                                 float* __restrict__ o) {
  int i = blockIdx.x * blockDim.x + threadIdx.x;
  if (i >= QKVS) return;
  float v;
  if (i < QCOLS) v = bq[i];
  else if (i < QCOLS + KCOLS) v = bk[i - QCOLS];
  else v = bv[i - QCOLS - KCOLS];
  o[i] = v;
}

// ---------------------------------------------------------------------------
// bf16 MFMA GEMM: C[M,N] = A[M,K] @ W[N,K]^T (+ bias), fp32 out.
// ---------------------------------------------------------------------------
#define GTM 128
#define GTN 128
#define GTK 32

__global__ __launch_bounds__(256) void gemm_bf16_kernel(
    const short* __restrict__ A, const short* __restrict__ W,
    const float* __restrict__ bias, float* __restrict__ C,
    int M, int N, int K) {
  __shared__ short As[GTM * GTK];
  __shared__ short Bs[GTN * GTK];

  const int tid = threadIdx.x;
  const int wave = tid >> 6;
  const int lane = tid & 63;
  const int l15 = lane & 15;
  const int quad = lane >> 4;
  const int m0 = blockIdx.y * GTM;
  const int n0 = blockIdx.x * GTN;
  const int wm = (wave >> 1) * 64;
  const int wn = (wave & 1) * 64;

  f32x4 acc[4][4] = {};

  const int c0 = tid, c1 = tid + 256;
  const int r0 = c0 >> 2, ko0 = (c0 & 3) * 8;
  const int r1 = c1 >> 2, ko1 = (c1 & 3) * 8;
  const short* Ag0 = A + (size_t)(m0 + r0) * K + ko0;
  const short* Ag1 = A + (size_t)(m0 + r1) * K + ko1;
  const short* Wg0 = W + (size_t)(n0 + r0) * K + ko0;
  const short* Wg1 = W + (size_t)(n0 + r1) * K + ko1;

  for (int k0 = 0; k0 < K; k0 += GTK) {
    __syncthreads();
    gload_lds16(Ag0 + k0, As + c0 * 8);
    gload_lds16(Ag1 + k0, As + c1 * 8);
    gload_lds16(Wg0 + k0, Bs + c0 * 8);
    gload_lds16(Wg1 + k0, Bs + c1 * 8);
    __syncthreads();

    bf16x8 af[4], bf[4];
#pragma unroll
    for (int i = 0; i < 4; ++i)
      af[i] = *(bf16x8*)(As + (wm + i * 16 + l15) * GTK + quad * 8);
#pragma unroll
    for (int j = 0; j < 4; ++j)
      bf[j] = *(bf16x8*)(Bs + (wn + j * 16 + l15) * GTK + quad * 8);
#pragma unroll
    for (int i = 0; i < 4; ++i)
#pragma unroll
      for (int j = 0; j < 4; ++j)
        acc[i][j] = __builtin_amdgcn_mfma_f32_16x16x32_bf16(af[i], bf[j],
                                                            acc[i][j], 0, 0, 0);
  }

#pragma unroll
  for (int j = 0; j < 4; ++j) {
    const int col = n0 + wn + j * 16 + l15;
    const float bv = bias ? bias[col] : 0.f;
#pragma unroll
    for (int i = 0; i < 4; ++i) {
      const int rowb = m0 + wm + i * 16 + quad * 4;
#pragma unroll
      for (int r = 0; r < 4; ++r)
        C[(size_t)(rowb + r) * N + col] = acc[i][j][r] + bv;
    }
  }
}

// ---------------------------------------------------------------------------
// RoPE in-place on fused qkv buffer.
// ---------------------------------------------------------------------------
__global__ void rope_kernel(float* __restrict__ p,
                            const float* __restrict__ cosp,
                            const float* __restrict__ sinp, int nh, int total) {
  int idx = blockIdx.x * blockDim.x + threadIdx.x;
  if (idx >= total) return;
  int d = idx & 31;
  int tmp = idx >> 5;
  int hh = tmp % nh;
  int row = tmp / nh;
  int l = row & (L - 1);

  float* base = p + (size_t)row * QKVS + hh * HD;
  float a = base[d];
  float b = base[d + 32];
  float cv = cosp[l * HD + d];
  float sv = sinp[l * HD + d];
  base[d] = a * cv - b * sv;
  base[d + 32] = b * cv + a * sv;
}

// ---------------------------------------------------------------------------
// Flash attention, bf16 MFMA, causal-paired strips + double-buffered staging.
// Block i handles Q strips qb1 = i*64 and qb2 = (31-i)*64 over the SAME
// staged K/V tiles -> uniform work per block, staging amortized 2x.
// ---------------------------------------------------------------------------
#define BQ 64
#define QT 16
#define BK 32

#define KSTR 66  // K tile [32 keys][64 d] bf16, padded
#define VSTR 34  // V^T tile [64 d][32 keys]
#define PSTR 36  // P tile per wave [16 q][32 keys]

__global__ __launch_bounds__(256) void attn_mfma_kernel(
    const float* __restrict__ qkv, __hip_bfloat16* __restrict__ ctx) {
  const int ipair = blockIdx.x;  // 0..15
  const int h = blockIdx.y;
  const int b = blockIdx.z;
  const int kvh = h / GROUPS;
  const int tid = threadIdx.x;
  const int wave = tid >> 6;
  const int lane = tid & 63;
  const int l15 = lane & 15;
  const int quad = lane >> 4;

  const int qb1 = ipair * BQ;                 // small strip
  const int qb2 = (L / BQ - 1 - ipair) * BQ;  // large strip

  __shared__ short Kt[2][BK * KSTR];
  __shared__ short Vt[2][HD * VSTR];
  __shared__ short Pt[4][16 * PSTR];

  const int qrb1 = qb1 + wave * QT;
  const int qrb2 = qb2 + wave * QT;

  // Q fragments (scale 1/8 folded in)
  bf16x8 qf1[2], qf2[2];
  {
    const float* qp1 = qkv + (size_t)(b * L + qrb1 + l15) * QKVS + h * HD;
    const float* qp2 = qkv + (size_t)(b * L + qrb2 + l15) * QKVS + h * HD;
#pragma unroll
    for (int half = 0; half < 2; ++half) {
      short t1[8], t2[8];
#pragma unroll
      for (int j = 0; j < 8; ++j) {
        t1[j] = f2bf(qp1[half * 32 + quad * 8 + j] * 0.125f);
        t2[j] = f2bf(qp2[half * 32 + quad * 8 + j] * 0.125f);
      }
      qf1[half] = *(bf16x8*)t1;
      qf2[half] = *(bf16x8*)t2;
    }
  }

  float m1[4] = {-INFINITY, -INFINITY, -INFINITY, -INFINITY};
  float m2[4] = {-INFINITY, -INFINITY, -INFINITY, -INFINITY};
  float l1[4] = {0.f, 0.f, 0.f, 0.f};
  float l2[4] = {0.f, 0.f, 0.f, 0.f};
  f32x4 o1[4] = {};
  f32x4 o2[4] = {};

  const float* kbase = qkv + (size_t)(b * L) * QKVS + QCOLS + kvh * HD;
  const float* vbase = kbase + KCOLS;

  const int ntiles = (qb2 + BQ) / BK;

  // staging prefetch registers
  float4 ka, kb;
  float vv[8];
  const int kd4 = (tid & 15) * 4;  // float4 offset along d
  const int kk_a = tid >> 4;       // key row 0..15 (and +16)
  const int vd = tid & 63;
  const int vk0 = tid >> 6;

  auto load_tile = [&](int j0) {
    const float* kp = kbase + (size_t)(j0 + kk_a) * QKVS + kd4;
    ka = *(const float4*)kp;
    kb = *(const float4*)(kp + (size_t)16 * QKVS);
#pragma unroll
    for (int s = 0; s < 8; ++s)
      vv[s] = vbase[(size_t)(j0 + vk0 + 4 * s) * QKVS + vd];
  };
  auto store_tile = [&](int bufi) {
    short4 s4;
    s4.x = f2bf(ka.x); s4.y = f2bf(ka.y); s4.z = f2bf(ka.z); s4.w = f2bf(ka.w);
    *(short4*)(&Kt[bufi][kk_a * KSTR + kd4]) = s4;
    s4.x = f2bf(kb.x); s4.y = f2bf(kb.y); s4.z = f2bf(kb.z); s4.w = f2bf(kb.w);
    *(short4*)(&Kt[bufi][(kk_a + 16) * KSTR + kd4]) = s4;
#pragma unroll
    for (int s = 0; s < 8; ++s)
      Vt[bufi][vd * VSTR + vk0 + 4 * s] = f2bf(vv[s]);
  };

  auto compute = [&](int j0, int bufi, int qrb, bf16x8* qf, float* mrow,
                     float* lrow, f32x4* oacc) {
    const short* Kb = Kt[bufi];
    const short* Vb = Vt[bufi];
    f32x4 S[2];
#pragma unroll
    for (int t = 0; t < 2; ++t) {
      bf16x8 b0 = *(const bf16x8*)(Kb + (t * 16 + l15) * KSTR + quad * 8);
      bf16x8 b1 = *(const bf16x8*)(Kb + (t * 16 + l15) * KSTR + 32 + quad * 8);
      f32x4 acc = {};
      acc = __builtin_amdgcn_mfma_f32_16x16x32_bf16(qf[0], b0, acc, 0, 0, 0);
      acc = __builtin_amdgcn_mfma_f32_16x16x32_bf16(qf[1], b1, acc, 0, 0, 0);
      S[t] = acc;
    }
    float p0v[4], p1v[4], al[4];
#pragma unroll
    for (int r = 0; r < 4; ++r) {
      const int qrow = qrb + quad * 4 + r;
      float s0 = (j0 + l15 <= qrow) ? S[0][r] : -INFINITY;
      float s1 = (j0 + 16 + l15 <= qrow) ? S[1][r] : -INFINITY;
      float mt = row_max16(fmaxf(s0, s1));
      float mn = fmaxf(mrow[r], mt);
      float p0 = __expf(s0 - mn);
      float p1 = __expf(s1 - mn);
      float a = __expf(mrow[r] - mn);
      lrow[r] = lrow[r] * a + p0 + p1;  // per-lane partial; reduced at end
      mrow[r] = mn;
      al[r] = a;
      p0v[r] = p0;
      p1v[r] = p1;
    }
    short* Pw = Pt[wave];
#pragma unroll
    for (int r = 0; r < 4; ++r) {
      Pw[(quad * 4 + r) * PSTR + l15] = f2bf(p0v[r]);
      Pw[(quad * 4 + r) * PSTR + 16 + l15] = f2bf(p1v[r]);
    }
#pragma unroll
    for (int c = 0; c < 4; ++c)
#pragma unroll
      for (int r = 0; r < 4; ++r) oacc[c][r] *= al[r];
    bf16x8 pfrag = *(const bf16x8*)(Pw + l15 * PSTR + quad * 8);
#pragma unroll
    for (int c = 0; c < 4; ++c) {
      bf16x8 vfrag = *(const bf16x8*)(Vb + (c * 16 + l15) * VSTR + quad * 8);
      oacc[c] =
          __builtin_amdgcn_mfma_f32_16x16x32_bf16(pfrag, vfrag, oacc[c], 0, 0, 0);
    }
  };

  load_tile(0);
  store_tile(0);
  __syncthreads();
  for (int t = 0; t < ntiles; ++t) {
    const int j0 = t * BK;
    const int cur = t & 1;
    if (t + 1 < ntiles) load_tile((t + 1) * BK);
    if (j0 <= qrb2 + QT - 1) compute(j0, cur, qrb2, qf2, m2, l2, o2);
    if (j0 <= qrb1 + QT - 1) compute(j0, cur, qrb1, qf1, m1, l1, o1);
    if (t + 1 < ntiles) store_tile(cur ^ 1);
    __syncthreads();
  }

  // epilogue
  __hip_bfloat16* cp = ctx + (size_t)(b * L) * QCOLS + h * HD;
#pragma unroll
  for (int r = 0; r < 4; ++r) {
    float inv1 = 1.0f / row_sum16(l1[r]);
    float inv2 = 1.0f / row_sum16(l2[r]);
    const int q1 = qrb1 + quad * 4 + r;
    const int q2 = qrb2 + quad * 4 + r;
#pragma unroll
    for (int c = 0; c < 4; ++c) {
      cp[(size_t)q1 * QCOLS + c * 16 + l15] = __float2bfloat16(o1[c][r] * inv1);
      cp[(size_t)q2 * QCOLS + c * 16 + l15] = __float2bfloat16(o2[c][r] * inv2);
    }
  }
}

// ---------------------------------------------------------------------------
extern "C" void kernel_launch(void* const* d_in, const int* in_sizes, int n_in,
                              void* d_out, int out_size, void* d_ws,
                              size_t ws_size, hipStream_t stream) {
  const float* x = (const float*)d_in[0];
  const float* cosp = (const float*)d_in[1];
  const float* sinp = (const float*)d_in[2];
  // d_in[3] = mask (unused)
  const float* wq = (const float*)d_in[4];
  const float* bq = (const float*)d_in[5];
  const float* wk = (const float*)d_in[6];
  const float* bk = (const float*)d_in[7];
  const float* wv = (const float*)d_in[8];
  const float* bv = (const float*)d_in[9];
  const float* wo = (const float*)d_in[10];
  float* out = (float*)d_out;

  char* ws = (char*)d_ws;
  float* qkv = (float*)ws;
  ws += (size_t)ROWS * QKVS * 4;
  short* xb = (short*)ws;
  ws += (size_t)ROWS * HID * 2;
  short* wqkvb = (short*)ws;
  ws += (size_t)QKVS * HID * 2;
  short* wob = (short*)ws;
  ws += (size_t)HID * QCOLS * 2;
  short* ctxb = (short*)ws;
  ws += (size_t)ROWS * QCOLS * 2;
  float* bqkv = (float*)ws;
  ws += QKVS * 4;

  {
    int n8 = ROWS * HID / 8;
    cast_bf16_kernel<<<(n8 + 255) / 256, 256, 0, stream>>>(x, xb, n8);
    int nq8 = QCOLS * HID / 8;
    cast_bf16_kernel<<<(nq8 + 255) / 256, 256, 0, stream>>>(wq, wqkvb, nq8);
    int nk8 = KCOLS * HID / 8;
    cast_bf16_kernel<<<(nk8 + 255) / 256, 256, 0, stream>>>(
        wk, wqkvb + (size_t)QCOLS * HID, nk8);
    cast_bf16_kernel<<<(nk8 + 255) / 256, 256, 0, stream>>>(
        wv, wqkvb + (size_t)(QCOLS + KCOLS) * HID, nk8);
    int no8 = HID * QCOLS / 8;
    cast_bf16_kernel<<<(no8 + 255) / 256, 256, 0, stream>>>(wo, wob, no8);
    pack_bias_kernel<<<(QKVS + 255) / 256, 256, 0, stream>>>(bq, bk, bv, bqkv);
  }

  gemm_bf16_kernel<<<dim3(QKVS / GTN, ROWS / GTM), 256, 0, stream>>>(
      xb, wqkvb, bqkv, qkv, ROWS, QKVS, HID);

  {
    int total_q = ROWS * NH * 32;
    rope_kernel<<<(total_q + 255) / 256, 256, 0, stream>>>(qkv, cosp, sinp, NH,
                                                           total_q);
    int total_k = ROWS * NKV * 32;
    rope_kernel<<<(total_k + 255) / 256, 256, 0, stream>>>(qkv + QCOLS, cosp,
                                                           sinp, NKV, total_k);
  }

  attn_mfma_kernel<<<dim3(L / BQ / 2, NH, B), 256, 0, stream>>>(
      qkv, (__hip_bfloat16*)ctxb);

  gemm_bf16_kernel<<<dim3(HID / GTN, ROWS / GTM), 256, 0, stream>>>(
      ctxb, wob, nullptr, out, ROWS, HID, QCOLS);
}

// Round 5
// 353.971 us; speedup vs baseline: 13.7067x; 1.4487x over previous
//
#include <hip/hip_runtime.h>
#include <hip/hip_bf16.h>
#include <math.h>

// Problem constants
#define B 4
#define L 2048
#define HID 896
#define NH 14
#define NKV 2
#define HD 64
#define GROUPS 7           // NH / NKV
#define QCOLS (NH * HD)    // 896
#define KCOLS (NKV * HD)   // 128
#define ROWS (B * L)       // 8192
#define QKVS 1152          // fused qkv row stride (896 q + 128 k + 128 v)

typedef __attribute__((ext_vector_type(8))) short bf16x8;
typedef __attribute__((ext_vector_type(4))) short bf16x4;
typedef __attribute__((ext_vector_type(4))) float f32x4;
typedef unsigned short ushort_t;
typedef unsigned int uint_t;

__device__ inline short f2bf(float f) {
  union { __hip_bfloat16 h; short s; } u;
  u.h = __float2bfloat16(f);
  return u.s;
}
__device__ inline float bf2f(ushort_t v) {
  union { ushort_t u; __hip_bfloat16 h; } x;
  x.u = v;
  return __bfloat162float(x.h);
}

__device__ inline void gload_lds16(const void* g, void* l) {
  __builtin_amdgcn_global_load_lds(
      (const __attribute__((address_space(1))) unsigned int*)g,
      (__attribute__((address_space(3))) unsigned int*)l, 16, 0, 0);
}

#if __has_builtin(__builtin_amdgcn_mfma_f32_16x16x16bf16_1k)
#define MFMA16(va, vb, vc) \
  __builtin_amdgcn_mfma_f32_16x16x16bf16_1k(va, vb, vc, 0, 0, 0)
#define HAVE_MFMA16 1
#else
#define HAVE_MFMA16 0
#endif

// ---------------------------------------------------------------------------
// fp32 -> bf16 cast, 8 elements / thread
// ---------------------------------------------------------------------------
__global__ void cast_bf16_kernel(const float* __restrict__ in,
                                 short* __restrict__ out, int n8) {
  int i = blockIdx.x * blockDim.x + threadIdx.x;
  if (i >= n8) return;
  const float4* p = (const float4*)in + (size_t)i * 2;
  float4 a = p[0], b = p[1];
  short s[8];
  s[0] = f2bf(a.x); s[1] = f2bf(a.y); s[2] = f2bf(a.z); s[3] = f2bf(a.w);
  s[4] = f2bf(b.x); s[5] = f2bf(b.y); s[6] = f2bf(b.z); s[7] = f2bf(b.w);
  *(bf16x8*)(out + (size_t)i * 8) = *(bf16x8*)s;
}

// pack bq|bk|bv into one [1152] fp32 vector
__global__ void pack_bias_kernel(const float* __restrict__ bq,
                                 const float* __restrict__ bk,
                                 const float* __restrict__ bv,
                                 float* __restrict__ o) {
  int i = blockIdx.x * blockDim.x + threadIdx.x;
  if (i >= QKVS) return;
  float v;
  if (i < QCOLS) v = bq[i];
  else if (i < QCOLS + KCOLS) v = bk[i - QCOLS];
  else v = bv[i - QCOLS - KCOLS];
  o[i] = v;
}

// ---------------------------------------------------------------------------
// bf16 MFMA GEMM: C[M,N] = A[M,K] @ W[N,K]^T (+ bias).
// Output fp32 (C) or bf16 (Cb) — exactly one must be non-null.
// ---------------------------------------------------------------------------
#define GTM 128
#define GTN 128
#define GTK 32

__global__ __launch_bounds__(256) void gemm_bf16_kernel(
    const short* __restrict__ A, const short* __restrict__ W,
    const float* __restrict__ bias, float* __restrict__ C,
    short* __restrict__ Cb, int M, int N, int K) {
  __shared__ short As[GTM * GTK];
  __shared__ short Bs[GTN * GTK];

  const int tid = threadIdx.x;
  const int wave = tid >> 6;
  const int lane = tid & 63;
  const int l15 = lane & 15;
  const int quad = lane >> 4;
  const int m0 = blockIdx.y * GTM;
  const int n0 = blockIdx.x * GTN;
  const int wm = (wave >> 1) * 64;
  const int wn = (wave & 1) * 64;

  f32x4 acc[4][4] = {};

  const int c0 = tid, c1 = tid + 256;
  const int r0 = c0 >> 2, ko0 = (c0 & 3) * 8;
  const int r1 = c1 >> 2, ko1 = (c1 & 3) * 8;
  const short* Ag0 = A + (size_t)(m0 + r0) * K + ko0;
  const short* Ag1 = A + (size_t)(m0 + r1) * K + ko1;
  const short* Wg0 = W + (size_t)(n0 + r0) * K + ko0;
  const short* Wg1 = W + (size_t)(n0 + r1) * K + ko1;

  for (int k0 = 0; k0 < K; k0 += GTK) {
    __syncthreads();
    gload_lds16(Ag0 + k0, As + c0 * 8);
    gload_lds16(Ag1 + k0, As + c1 * 8);
    gload_lds16(Wg0 + k0, Bs + c0 * 8);
    gload_lds16(Wg1 + k0, Bs + c1 * 8);
    __syncthreads();

    bf16x8 af[4], bfr[4];
#pragma unroll
    for (int i = 0; i < 4; ++i)
      af[i] = *(bf16x8*)(As + (wm + i * 16 + l15) * GTK + quad * 8);
#pragma unroll
    for (int j = 0; j < 4; ++j)
      bfr[j] = *(bf16x8*)(Bs + (wn + j * 16 + l15) * GTK + quad * 8);
#pragma unroll
    for (int i = 0; i < 4; ++i)
#pragma unroll
      for (int j = 0; j < 4; ++j)
        acc[i][j] = __builtin_amdgcn_mfma_f32_16x16x32_bf16(af[i], bfr[j],
                                                            acc[i][j], 0, 0, 0);
  }

#pragma unroll
  for (int j = 0; j < 4; ++j) {
    const int col = n0 + wn + j * 16 + l15;
    const float bv = bias ? bias[col] : 0.f;
#pragma unroll
    for (int i = 0; i < 4; ++i) {
      const int rowb = m0 + wm + i * 16 + quad * 4;
#pragma unroll
      for (int r = 0; r < 4; ++r) {
        const float val = acc[i][j][r] + bv;
        if (Cb)
          Cb[(size_t)(rowb + r) * N + col] = f2bf(val);
        else
          C[(size_t)(rowb + r) * N + col] = val;
      }
    }
  }
}

// ---------------------------------------------------------------------------
// RoPE + requantize on bf16 fused qkv buffer: src (raw) -> dst (roped).
// Q additionally scaled by 0.125*log2(e) (softmax done in base-2).
// One block per row: threads 0..511 -> 16 rope heads (q0..13, k0..1) x 32 d,
// threads 512..575 -> v copy (2 cols each).
// ---------------------------------------------------------------------------
#define QSCALE 0.18033688011112042f  // 0.125 * log2(e)

__global__ __launch_bounds__(576) void rope_cast_kernel(
    const ushort_t* __restrict__ src, ushort_t* __restrict__ dst,
    const float* __restrict__ cosp, const float* __restrict__ sinp) {
  const int row = blockIdx.x;
  const int j = threadIdx.x;
  const ushort_t* s = src + (size_t)row * QKVS;
  ushort_t* d = dst + (size_t)row * QKVS;
  const int l = row & (L - 1);
  if (j < 512) {
    const int hh = j >> 5;
    const int dd = j & 31;
    const int c0 = hh * 64 + dd;
    const float a = bf2f(s[c0]);
    const float b2 = bf2f(s[c0 + 32]);
    const float cv = cosp[l * HD + dd];
    const float sv = sinp[l * HD + dd];
    const float sc = (hh < NH) ? QSCALE : 1.0f;
    d[c0] = (ushort_t)f2bf((a * cv - b2 * sv) * sc);
    d[c0 + 32] = (ushort_t)f2bf((b2 * cv + a * sv) * sc);
  } else {
    const int c = 1024 + (j - 512) * 2;
    *(uint_t*)(&d[c]) = *(const uint_t*)(&s[c]);
  }
}

// ---------------------------------------------------------------------------
// Flash attention, S^T formulation (no P LDS round-trip).
//   S^T[key][q] = mfma_16x16x32(A=K-frag, B=Q-frag): col=q=l15,
//   row=key=quad*4+r  ==  B-layout of mfma_16x16x16 -> feed PV directly.
//   O^T[d][q] = mfma_16x16x16(A=V^T-frag, B=P^T).
// Softmax state m,l: one scalar per lane (q = l15); max-reduce = 2 shuffles
// (xor16, xor32); l-sum deferred to epilogue.
// Block = 4 waves; strips (ipair, 31-ipair) share staged K/V tiles and the
// per-tile K/V fragment loads.
// ---------------------------------------------------------------------------
#define BQ 64
#define QT 16
#define BK 32

#define KSTR 66  // K tile [32 keys][64 d] bf16, padded (2-way banks)
#define VSTR 34  // V^T tile [64 d][32 keys]
#define PSTR 36  // fallback P tile per wave [16 q][32 keys]

__global__ __launch_bounds__(256) void attn_mfma_kernel(
    const ushort_t* __restrict__ qkv, __hip_bfloat16* __restrict__ ctx) {
  const int ipair = blockIdx.x;  // 0..15
  const int h = blockIdx.y;
  const int b = blockIdx.z;
  const int kvh = h / GROUPS;
  const int tid = threadIdx.x;
  const int wave = tid >> 6;
  const int lane = tid & 63;
  const int l15 = lane & 15;
  const int quad = lane >> 4;

  const int qb1 = ipair * BQ;                 // small strip
  const int qb2 = (L / BQ - 1 - ipair) * BQ;  // large strip

  __shared__ short Kt[2][BK * KSTR];
  __shared__ short Vt[2][HD * VSTR];
#if !HAVE_MFMA16
  __shared__ short Pt[4][16 * PSTR];
#endif

  const int qrb1 = qb1 + wave * QT;
  const int qrb2 = qb2 + wave * QT;

  // Q B-fragments: lane holds Q[qrb+l15][half*32+quad*8+j], pre-scaled.
  bf16x8 qf1[2], qf2[2];
  {
    const ushort_t* qp1 = qkv + (size_t)(b * L + qrb1 + l15) * QKVS + h * HD;
    const ushort_t* qp2 = qkv + (size_t)(b * L + qrb2 + l15) * QKVS + h * HD;
    qf1[0] = *(const bf16x8*)(qp1 + quad * 8);
    qf1[1] = *(const bf16x8*)(qp1 + 32 + quad * 8);
    qf2[0] = *(const bf16x8*)(qp2 + quad * 8);
    qf2[1] = *(const bf16x8*)(qp2 + 32 + quad * 8);
  }

  float m1 = -INFINITY, m2 = -INFINITY;
  float l1 = 0.f, l2 = 0.f;
  f32x4 o1[4] = {};  // O^T: oacc[c][r] = O[q=l15][d=c*16+quad*4+r]
  f32x4 o2[4] = {};

  const ushort_t* kb = qkv + (size_t)(b * L) * QKVS + QCOLS + kvh * HD;
  const ushort_t* vb = kb + KCOLS;

  const int ntiles = (qb2 + BQ) / BK;

  // staging prefetch registers (bf16 input: pure copies)
  uint4 kreg;
  ushort_t vreg[8];
  const int kk = tid >> 3;        // key row 0..31
  const int kd8 = (tid & 7) * 8;  // short offset along d
  const int vd = tid & 63;
  const int vk0 = tid >> 6;  // wave-uniform

  auto load_tile = [&](int j0) {
    kreg = *(const uint4*)(kb + (size_t)(j0 + kk) * QKVS + kd8);
#pragma unroll
    for (int s = 0; s < 8; ++s)
      vreg[s] = vb[(size_t)(j0 + vk0 + 4 * s) * QKVS + vd];
  };
  auto store_tile = [&](int bufi) {
    *(uint4*)(&Kt[bufi][kk * KSTR + kd8]) = kreg;
#pragma unroll
    for (int s = 0; s < 8; ++s)
      Vt[bufi][vd * VSTR + vk0 + 4 * s] = (short)vreg[s];
  };

#if HAVE_MFMA16
#define VF_T bf16x4(&vf)[4][2]
#else
#define VF_T bf16x8(&vf)[4]
#endif
  auto do_strip = [&](int j0, int qrb, bf16x8* qf, float& m, float& lsum,
                      f32x4* oacc, bf16x8(&kf)[2][2], VF_T) {
    // S^T = K Q^T (2 key-subtiles x 2 d-halves)
    f32x4 St[2];
#pragma unroll
    for (int tt = 0; tt < 2; ++tt) {
      f32x4 a = {};
      a = __builtin_amdgcn_mfma_f32_16x16x32_bf16(kf[tt][0], qf[0], a, 0, 0, 0);
      a = __builtin_amdgcn_mfma_f32_16x16x32_bf16(kf[tt][1], qf[1], a, 0, 0, 0);
      St[tt] = a;
    }
    // causal mask: key_local = tt*16 + quad*4 + r valid iff <= lim
    const int lim = qrb + l15 - j0 - quad * 4;
    float s[8];
#pragma unroll
    for (int tt = 0; tt < 2; ++tt)
#pragma unroll
      for (int r = 0; r < 4; ++r)
        s[tt * 4 + r] = (tt * 16 + r <= lim) ? St[tt][r] : -INFINITY;
    float mt = s[0];
#pragma unroll
    for (int i = 1; i < 8; ++i) mt = fmaxf(mt, s[i]);
    mt = fmaxf(mt, __shfl_xor(mt, 16));
    mt = fmaxf(mt, __shfl_xor(mt, 32));
    const float mn = fmaxf(m, mt);
    const float al = exp2f(m - mn);
    m = mn;
    float p[8], ps = 0.f;
#pragma unroll
    for (int i = 0; i < 8; ++i) {
      p[i] = exp2f(s[i] - mn);
      ps += p[i];
    }
    lsum = lsum * al + ps;  // per-lane partial; cross-quad reduce at end
#pragma unroll
    for (int c = 0; c < 4; ++c)
#pragma unroll
      for (int r = 0; r < 4; ++r) oacc[c][r] *= al;
    bf16x4 pk[2];
#pragma unroll
    for (int tt = 0; tt < 2; ++tt) {
      bf16x4 v;
      v[0] = f2bf(p[tt * 4 + 0]);
      v[1] = f2bf(p[tt * 4 + 1]);
      v[2] = f2bf(p[tt * 4 + 2]);
      v[3] = f2bf(p[tt * 4 + 3]);
      pk[tt] = v;
    }
#if HAVE_MFMA16
#pragma unroll
    for (int tt = 0; tt < 2; ++tt)
#pragma unroll
      for (int c = 0; c < 4; ++c) oacc[c] = MFMA16(vf[c][tt], pk[tt], oacc[c]);
#else
    short* Pw = Pt[wave];
    *(bf16x4*)(&Pw[l15 * PSTR + quad * 4]) = pk[0];
    *(bf16x4*)(&Pw[l15 * PSTR + 16 + quad * 4]) = pk[1];
    union { bf16x8 v; uint_t u[4]; } pu;
#pragma unroll
    for (int w = 0; w < 4; ++w)
      pu.u[w] = *(const uint_t*)(&Pw[l15 * PSTR + quad * 8 + 2 * w]);
#pragma unroll
    for (int c = 0; c < 4; ++c)
      oacc[c] =
          __builtin_amdgcn_mfma_f32_16x16x32_bf16(vf[c], pu.v, oacc[c], 0, 0, 0);
#endif
  };

  load_tile(0);
  store_tile(0);
  __syncthreads();
  for (int t = 0; t < ntiles; ++t) {
    const int j0 = t * BK;
    const int cur = t & 1;
    if (t + 1 < ntiles) load_tile((t + 1) * BK);
    if (j0 <= qrb2 + QT - 1) {
      const short* Kb = Kt[cur];
      const short* Vb = Vt[cur];
      // shared K fragments (4B-aligned loads; LDS rows padded)
      bf16x8 kf[2][2];
#pragma unroll
      for (int tt = 0; tt < 2; ++tt)
#pragma unroll
        for (int hf = 0; hf < 2; ++hf) {
          const short* kp = &Kb[(tt * 16 + l15) * KSTR + hf * 32 + quad * 8];
          union { bf16x8 v; uint_t u[4]; } ku;
#pragma unroll
          for (int w = 0; w < 4; ++w) ku.u[w] = *(const uint_t*)(kp + 2 * w);
          kf[tt][hf] = ku.v;
        }
      // shared V^T fragments
#if HAVE_MFMA16
      bf16x4 vf[4][2];
#pragma unroll
      for (int c = 0; c < 4; ++c)
#pragma unroll
        for (int tt = 0; tt < 2; ++tt) {
          const short* vp = &Vb[(c * 16 + l15) * VSTR + tt * 16 + quad * 4];
          union { bf16x4 v; uint_t u[2]; } vu;
          vu.u[0] = *(const uint_t*)(vp);
          vu.u[1] = *(const uint_t*)(vp + 2);
          vf[c][tt] = vu.v;
        }
#else
      bf16x8 vf[4];
#pragma unroll
      for (int c = 0; c < 4; ++c) {
        const short* vp = &Vb[(c * 16 + l15) * VSTR + quad * 8];
        union { bf16x8 v; uint_t u[4]; } vu;
#pragma unroll
        for (int w = 0; w < 4; ++w) vu.u[w] = *(const uint_t*)(vp + 2 * w);
        vf[c] = vu.v;
      }
#endif
      do_strip(j0, qrb2, qf2, m2, l2, o2, kf, vf);
      if (j0 <= qrb1 + QT - 1) do_strip(j0, qrb1, qf1, m1, l1, o1, kf, vf);
    }
    if (t + 1 < ntiles) store_tile(cur ^ 1);
    __syncthreads();
  }

  // epilogue: reduce l across quads, normalize, store O (bf16x4 per c)
  float s1 = l1;
  s1 += __shfl_xor(s1, 16);
  s1 += __shfl_xor(s1, 32);
  float s2 = l2;
  s2 += __shfl_xor(s2, 16);
  s2 += __shfl_xor(s2, 32);
  const float inv1 = 1.0f / s1;
  const float inv2 = 1.0f / s2;
  short* cb = (short*)ctx + (size_t)(b * L) * QCOLS + h * HD;
#pragma unroll
  for (int c = 0; c < 4; ++c) {
    bf16x4 w1, w2;
#pragma unroll
    for (int r = 0; r < 4; ++r) {
      w1[r] = f2bf(o1[c][r] * inv1);
      w2[r] = f2bf(o2[c][r] * inv2);
    }
    *(bf16x4*)(cb + (size_t)(qrb1 + l15) * QCOLS + c * 16 + quad * 4) = w1;
    *(bf16x4*)(cb + (size_t)(qrb2 + l15) * QCOLS + c * 16 + quad * 4) = w2;
  }
}

// ---------------------------------------------------------------------------
extern "C" void kernel_launch(void* const* d_in, const int* in_sizes, int n_in,
                              void* d_out, int out_size, void* d_ws,
                              size_t ws_size, hipStream_t stream) {
  const float* x = (const float*)d_in[0];
  const float* cosp = (const float*)d_in[1];
  const float* sinp = (const float*)d_in[2];
  // d_in[3] = mask (unused)
  const float* wq = (const float*)d_in[4];
  const float* bq = (const float*)d_in[5];
  const float* wk = (const float*)d_in[6];
  const float* bk = (const float*)d_in[7];
  const float* wv = (const float*)d_in[8];
  const float* bv = (const float*)d_in[9];
  const float* wo = (const float*)d_in[10];
  float* out = (float*)d_out;

  char* ws = (char*)d_ws;
  ushort_t* qkv_raw = (ushort_t*)ws;  // [ROWS][QKVS] bf16, pre-rope
  ws += (size_t)ROWS * QKVS * 2;
  ushort_t* qkvb = (ushort_t*)ws;     // [ROWS][QKVS] bf16, roped + q-scaled
  ws += (size_t)ROWS * QKVS * 2;
  short* xb = (short*)ws;
  ws += (size_t)ROWS * HID * 2;
  short* wqkvb = (short*)ws;
  ws += (size_t)QKVS * HID * 2;
  short* wob = (short*)ws;
  ws += (size_t)HID * QCOLS * 2;
  short* ctxb = (short*)ws;
  ws += (size_t)ROWS * QCOLS * 2;
  float* bqkv = (float*)ws;
  ws += QKVS * 4;

  {
    int n8 = ROWS * HID / 8;
    cast_bf16_kernel<<<(n8 + 255) / 256, 256, 0, stream>>>(x, xb, n8);
    int nq8 = QCOLS * HID / 8;
    cast_bf16_kernel<<<(nq8 + 255) / 256, 256, 0, stream>>>(wq, wqkvb, nq8);
    int nk8 = KCOLS * HID / 8;
    cast_bf16_kernel<<<(nk8 + 255) / 256, 256, 0, stream>>>(
        wk, wqkvb + (size_t)QCOLS * HID, nk8);
    cast_bf16_kernel<<<(nk8 + 255) / 256, 256, 0, stream>>>(
        wv, wqkvb + (size_t)(QCOLS + KCOLS) * HID, nk8);
    int no8 = HID * QCOLS / 8;
    cast_bf16_kernel<<<(no8 + 255) / 256, 256, 0, stream>>>(wo, wob, no8);
    pack_bias_kernel<<<(QKVS + 255) / 256, 256, 0, stream>>>(bq, bk, bv, bqkv);
  }

  // fused QKV projection -> bf16
  gemm_bf16_kernel<<<dim3(QKVS / GTN, ROWS / GTM), 256, 0, stream>>>(
      xb, wqkvb, bqkv, nullptr, (short*)qkv_raw, ROWS, QKVS, HID);

  // RoPE + q-scale (bf16 -> bf16)
  rope_cast_kernel<<<ROWS, 576, 0, stream>>>(qkv_raw, qkvb, cosp, sinp);

  // attention -> bf16 ctx
  attn_mfma_kernel<<<dim3(L / BQ / 2, NH, B), 256, 0, stream>>>(
      qkvb, (__hip_bfloat16*)ctxb);

  // output projection -> fp32 out
  gemm_bf16_kernel<<<dim3(HID / GTN, ROWS / GTM), 256, 0, stream>>>(
      ctxb, wob, nullptr, out, nullptr, ROWS, HID, QCOLS);
}

// Round 8
// 309.641 us; speedup vs baseline: 15.6690x; 1.1432x over previous
//
#include <hip/hip_runtime.h>
#include <hip/hip_bf16.h>
#include <math.h>

// Problem constants
#define B 4
#define L 2048
#define HID 896
#define NH 14
#define NKV 2
#define HD 64
#define GROUPS 7           // NH / NKV
#define QCOLS (NH * HD)    // 896
#define KCOLS (NKV * HD)   // 128
#define ROWS (B * L)       // 8192
#define QKVS 1152          // fused qkv row stride (896 q + 128 k + 128 v)

typedef __attribute__((ext_vector_type(8))) short bf16x8;
typedef __attribute__((ext_vector_type(4))) short bf16x4;
typedef __attribute__((ext_vector_type(4))) float f32x4;
typedef unsigned short ushort_t;
typedef unsigned int uint_t;

__device__ inline short f2bf(float f) {
  union { __hip_bfloat16 h; short s; } u;
  u.h = __float2bfloat16(f);
  return u.s;
}

__device__ inline uint_t pack2_bf16(float a, float b) {
  return (uint_t)(ushort_t)f2bf(a) | ((uint_t)(ushort_t)f2bf(b) << 16);
}

#if defined(__HIP_DEVICE_COMPILE__)
__device__ inline f32x4 mfma16(bf16x4 a, bf16x4 b, f32x4 c) {
  return __builtin_amdgcn_mfma_f32_16x16x16bf16_1k(a, b, c, 0, 0, 0);
}
#define EXP2(x) __builtin_amdgcn_exp2f(x)
#else
// host-pass stubs (never executed; keep the parser happy)
__device__ inline f32x4 mfma16(bf16x4 a, bf16x4 b, f32x4 c) { return c; }
#define EXP2(x) exp2f(x)
#endif

__device__ inline void gload_lds16(const void* g, void* l) {
  __builtin_amdgcn_global_load_lds(
      (const __attribute__((address_space(1))) unsigned int*)g,
      (__attribute__((address_space(3))) unsigned int*)l, 16, 0, 0);
}

// ---------------------------------------------------------------------------
// fp32 -> bf16 cast, 8 elements / thread
// ---------------------------------------------------------------------------
__global__ void cast_bf16_kernel(const float* __restrict__ in,
                                 short* __restrict__ out, int n8) {
  int i = blockIdx.x * blockDim.x + threadIdx.x;
  if (i >= n8) return;
  const float4* p = (const float4*)in + (size_t)i * 2;
  float4 a = p[0], b = p[1];
  short s[8];
  s[0] = f2bf(a.x); s[1] = f2bf(a.y); s[2] = f2bf(a.z); s[3] = f2bf(a.w);
  s[4] = f2bf(b.x); s[5] = f2bf(b.y); s[6] = f2bf(b.z); s[7] = f2bf(b.w);
  *(bf16x8*)(out + (size_t)i * 8) = *(bf16x8*)s;
}

// pack bq|bk|bv into one [1152] fp32 vector
__global__ void pack_bias_kernel(const float* __restrict__ bq,
                                 const float* __restrict__ bk,
                                 const float* __restrict__ bv,
                                 float* __restrict__ o) {
  int i = blockIdx.x * blockDim.x + threadIdx.x;
  if (i >= QKVS) return;
  float v;
  if (i < QCOLS) v = bq[i];
  else if (i < QCOLS + KCOLS) v = bk[i - QCOLS];
  else v = bv[i - QCOLS - KCOLS];
  o[i] = v;
}

// ---------------------------------------------------------------------------
// bf16 MFMA GEMM: C[M,N] = A[M,K] @ W[N,K]^T (+ bias).
// ROPE=true: bf16 out with fused RoPE (+QSCALE on q heads); else fp32 out.
// Wave's 64 output cols = exactly one 64-wide head (tiles 128, heads 64).
// ---------------------------------------------------------------------------
#define GTM 128
#define GTN 128
#define GTK 32
#define QSCALE 0.18033688011112042f  // 0.125 * log2(e)

template <bool ROPE>
__global__ __launch_bounds__(256) void gemm_bf16_kernel(
    const short* __restrict__ A, const short* __restrict__ W,
    const float* __restrict__ bias, float* __restrict__ C,
    short* __restrict__ Cb, const float* __restrict__ cosp,
    const float* __restrict__ sinp, int M, int N, int K) {
  __shared__ short As[GTM * GTK];
  __shared__ short Bs[GTN * GTK];

  const int tid = threadIdx.x;
  const int wave = tid >> 6;
  const int lane = tid & 63;
  const int l15 = lane & 15;
  const int quad = lane >> 4;
  const int m0 = blockIdx.y * GTM;
  const int n0 = blockIdx.x * GTN;
  const int wm = (wave >> 1) * 64;
  const int wn = (wave & 1) * 64;

  f32x4 acc[4][4] = {};

  const int c0 = tid, c1 = tid + 256;
  const int r0 = c0 >> 2, ko0 = (c0 & 3) * 8;
  const int r1 = c1 >> 2, ko1 = (c1 & 3) * 8;
  const short* Ag0 = A + (size_t)(m0 + r0) * K + ko0;
  const short* Ag1 = A + (size_t)(m0 + r1) * K + ko1;
  const short* Wg0 = W + (size_t)(n0 + r0) * K + ko0;
  const short* Wg1 = W + (size_t)(n0 + r1) * K + ko1;

  for (int k0 = 0; k0 < K; k0 += GTK) {
    __syncthreads();
    gload_lds16(Ag0 + k0, As + c0 * 8);
    gload_lds16(Ag1 + k0, As + c1 * 8);
    gload_lds16(Wg0 + k0, Bs + c0 * 8);
    gload_lds16(Wg1 + k0, Bs + c1 * 8);
    __syncthreads();

    bf16x8 af[4], bfr[4];
#pragma unroll
    for (int i = 0; i < 4; ++i)
      af[i] = *(bf16x8*)(As + (wm + i * 16 + l15) * GTK + quad * 8);
#pragma unroll
    for (int j = 0; j < 4; ++j)
      bfr[j] = *(bf16x8*)(Bs + (wn + j * 16 + l15) * GTK + quad * 8);
#pragma unroll
    for (int i = 0; i < 4; ++i)
#pragma unroll
      for (int j = 0; j < 4; ++j)
        acc[i][j] = __builtin_amdgcn_mfma_f32_16x16x32_bf16(af[i], bfr[j],
                                                            acc[i][j], 0, 0, 0);
  }

  const int col0 = n0 + wn + l15;
  if (ROPE) {
    const int hw = (n0 + wn) >> 6;  // head index within qkv row
    float bv[4];
#pragma unroll
    for (int j = 0; j < 4; ++j) bv[j] = bias[col0 + 16 * j];
    if (hw < NH + NKV) {
      // q/k head: rope pairs (d, d+32) = (j, j+2) in-register
      const float sc = (hw < NH) ? QSCALE : 1.0f;
#pragma unroll
      for (int i = 0; i < 4; ++i) {
        const int rowb = m0 + wm + i * 16 + quad * 4;
#pragma unroll
        for (int r = 0; r < 4; ++r) {
          const int row = rowb + r;
          const int l = row & (L - 1);
          const float* cp = cosp + l * HD + l15;
          const float* sp = sinp + l * HD + l15;
#pragma unroll
          for (int j = 0; j < 2; ++j) {
            const float cv = cp[16 * j];
            const float sv = sp[16 * j];
            const float a = acc[i][j][r] + bv[j];
            const float b2 = acc[i][j + 2][r] + bv[j + 2];
            Cb[(size_t)row * N + col0 + 16 * j] = f2bf((a * cv - b2 * sv) * sc);
            Cb[(size_t)row * N + col0 + 16 * j + 32] =
                f2bf((b2 * cv + a * sv) * sc);
          }
        }
      }
    } else {
      // v head: plain bias + bf16 store
#pragma unroll
      for (int j = 0; j < 4; ++j)
#pragma unroll
        for (int i = 0; i < 4; ++i) {
          const int rowb = m0 + wm + i * 16 + quad * 4;
#pragma unroll
          for (int r = 0; r < 4; ++r)
            Cb[(size_t)(rowb + r) * N + col0 + 16 * j] =
                f2bf(acc[i][j][r] + bv[j]);
        }
    }
  } else {
#pragma unroll
    for (int j = 0; j < 4; ++j) {
      const int col = col0 + 16 * j;
      const float bv = bias ? bias[col] : 0.f;
#pragma unroll
      for (int i = 0; i < 4; ++i) {
        const int rowb = m0 + wm + i * 16 + quad * 4;
#pragma unroll
        for (int r = 0; r < 4; ++r)
          C[(size_t)(rowb + r) * N + col] = acc[i][j][r] + bv;
      }
    }
  }
}

// ---------------------------------------------------------------------------
// Flash attention, S^T formulation, BK=64 key tiles, causal-paired strips.
//   S^T[key][q] = mfma_16x16x32(A=K, B=Q)  (C: col=q=l15, row=key=quad*4+r)
//   C-layout == B/A-layout of mfma_16x16x16 -> PV with zero LDS round-trip:
//   O^T[d][q] += mfma_16x16x16(A=V^T-frag, B=P^T-frag).
// K tile: XOR-swizzled (8-short granule) -> conflict-free b128 r/w.
// V^T tile: VSTR=70 (odd-dword stride) -> 2-way (free) b16 writes/b32 reads.
// Local-max exp trick: exps issue before the 2 cross-quad shuffles.
// ---------------------------------------------------------------------------
#define BK 64
#define VSTR 70

__global__ __launch_bounds__(256, 3) void attn_mfma_kernel(
    const ushort_t* __restrict__ qkv, ushort_t* __restrict__ ctx) {
  const int ipair = blockIdx.x;  // 0..15
  const int h = blockIdx.y;
  const int b = blockIdx.z;
  const int kvh = h / GROUPS;
  const int tid = threadIdx.x;
  const int wave = tid >> 6;
  const int lane = tid & 63;
  const int l15 = lane & 15;
  const int quad = lane >> 4;

  const int lt1 = ipair;                // last tile index, strip 1
  const int lt2 = (L / BK - 1) - ipair; // last tile index, strip 2
  const int qrb1 = lt1 * BK + wave * 16;
  const int qrb2 = lt2 * BK + wave * 16;

  __shared__ short Kt[2][BK * 64];
  __shared__ short Vt[2][HD * VSTR];

  // Q fragments (QSCALE pre-folded by projection kernel)
  bf16x8 qf1[2], qf2[2];
  {
    const ushort_t* qp1 = qkv + (size_t)(b * L + qrb1 + l15) * QKVS + h * HD;
    const ushort_t* qp2 = qkv + (size_t)(b * L + qrb2 + l15) * QKVS + h * HD;
    qf1[0] = *(const bf16x8*)(qp1 + quad * 8);
    qf1[1] = *(const bf16x8*)(qp1 + 32 + quad * 8);
    qf2[0] = *(const bf16x8*)(qp2 + quad * 8);
    qf2[1] = *(const bf16x8*)(qp2 + 32 + quad * 8);
  }

  float m1 = -INFINITY, m2 = -INFINITY, l1 = 0.f, l2 = 0.f;
  f32x4 o1[4] = {}, o2[4] = {};

  const ushort_t* kb = qkv + (size_t)(b * L) * QKVS + QCOLS + kvh * HD;
  const ushort_t* vb = kb + KCOLS;

  // staging assignments
  const int skey = tid >> 2;            // K: key row 0..63
  const int sblk = (tid & 3) * 2;       // K: first 8-d block
  const int ksw0 = (sblk ^ (skey & 7)) * 8;
  const int ksw1 = ((sblk + 1) ^ (skey & 7)) * 8;
  const int vd = tid & 63;              // V: d
  const int vk0 = wave * 16;            // V: key band base (wave-uniform)

  uint4 kr0, kr1;
  ushort_t vr[16];

  auto load_tile = [&](int j0) {
    const ushort_t* kp = kb + (size_t)(j0 + skey) * QKVS + sblk * 8;
    kr0 = *(const uint4*)(kp);
    kr1 = *(const uint4*)(kp + 8);
    const ushort_t* vp = vb + (size_t)(j0 + vk0) * QKVS + vd;
#pragma unroll
    for (int s = 0; s < 16; ++s) vr[s] = vp[(size_t)s * QKVS];
  };
  auto store_tile = [&](int bufi) {
    *(uint4*)(&Kt[bufi][skey * 64 + ksw0]) = kr0;
    *(uint4*)(&Kt[bufi][skey * 64 + ksw1]) = kr1;
#pragma unroll
    for (int s = 0; s < 16; ++s) Vt[bufi][vd * VSTR + vk0 + s] = (short)vr[s];
  };

  auto softmax = [&](f32x4(&St)[4], float& m, float& lsum, f32x4(&oacc)[4],
                     int limq, uint_t* pku) {
    float s[16];
#pragma unroll
    for (int tt = 0; tt < 4; ++tt)
#pragma unroll
      for (int r = 0; r < 4; ++r)
        s[tt * 4 + r] = (tt * 16 + r <= limq) ? St[tt][r] : -1e30f;
    float mt = fmaxf(s[0], s[1]);
#pragma unroll
    for (int i = 2; i < 16; ++i) mt = fmaxf(mt, s[i]);
    // exps on local max first (overlaps the cross-quad shuffles)
    float pl[16], psl = 0.f;
#pragma unroll
    for (int i = 0; i < 16; ++i) {
      pl[i] = EXP2(s[i] - mt);
      psl += pl[i];
    }
    float mg = fmaxf(mt, __shfl_xor(mt, 16));
    mg = fmaxf(mg, __shfl_xor(mg, 32));
    const float mn = fmaxf(m, mg);
    const float f = EXP2(mt - mn);
    const float al = EXP2(m - mn);
    m = mn;
    lsum = lsum * al + psl * f;
#pragma unroll
    for (int c = 0; c < 4; ++c)
#pragma unroll
      for (int r = 0; r < 4; ++r) oacc[c][r] *= al;
#pragma unroll
    for (int tt = 0; tt < 4; ++tt) {
      pku[2 * tt] = pack2_bf16(pl[4 * tt] * f, pl[4 * tt + 1] * f);
      pku[2 * tt + 1] = pack2_bf16(pl[4 * tt + 2] * f, pl[4 * tt + 3] * f);
    }
  };

  load_tile(0);
  store_tile(0);
  __syncthreads();

  for (int t = 0; t <= lt2; ++t) {
    const int j0 = t * BK;
    const int cur = t & 1;
    if (t < lt2) load_tile(j0 + BK);

    const short* Kb = Kt[cur];
    const short* Vb = Vt[cur];
    const bool a1 = (t <= lt1);

    // ---- S^T for both strips, consuming K frags per-tt ----
    f32x4 St2[4], St1[4];
#pragma unroll
    for (int tt = 0; tt < 4; ++tt) {
      const int key = tt * 16 + l15;
      const short* krow = Kb + key * 64;
      bf16x8 k0 = *(const bf16x8*)(krow + (quad ^ (key & 7)) * 8);
      bf16x8 k1 = *(const bf16x8*)(krow + ((4 + quad) ^ (key & 7)) * 8);
      f32x4 a = {};
      a = __builtin_amdgcn_mfma_f32_16x16x32_bf16(k0, qf2[0], a, 0, 0, 0);
      a = __builtin_amdgcn_mfma_f32_16x16x32_bf16(k1, qf2[1], a, 0, 0, 0);
      St2[tt] = a;
      if (a1) {
        f32x4 c = {};
        c = __builtin_amdgcn_mfma_f32_16x16x32_bf16(k0, qf1[0], c, 0, 0, 0);
        c = __builtin_amdgcn_mfma_f32_16x16x32_bf16(k1, qf1[1], c, 0, 0, 0);
        St1[tt] = c;
      }
    }

    uint_t pk2[8], pk1[8];
    softmax(St2, m2, l2, o2, (t == lt2) ? (qrb2 + l15 - j0 - quad * 4) : 63,
            pk2);
    if (a1)
      softmax(St1, m1, l1, o1, (t == lt1) ? (qrb1 + l15 - j0 - quad * 4) : 63,
              pk1);

    // ---- PV: O^T += V^T P^T, V frags shared between strips ----
#pragma unroll
    for (int c = 0; c < 4; ++c) {
      const short* vrow = Vb + (c * 16 + l15) * VSTR + quad * 4;
#pragma unroll
      for (int tt = 0; tt < 4; ++tt) {
        union { bf16x4 v; uint_t u[2]; } vfu;
        vfu.u[0] = *(const uint_t*)(vrow + tt * 16);
        vfu.u[1] = *(const uint_t*)(vrow + tt * 16 + 2);
        union { bf16x4 v; uint_t u[2]; } pa;
        pa.u[0] = pk2[2 * tt];
        pa.u[1] = pk2[2 * tt + 1];
        o2[c] = mfma16(vfu.v, pa.v, o2[c]);
        if (a1) {
          union { bf16x4 v; uint_t u[2]; } pb;
          pb.u[0] = pk1[2 * tt];
          pb.u[1] = pk1[2 * tt + 1];
          o1[c] = mfma16(vfu.v, pb.v, o1[c]);
        }
      }
    }

    if (t < lt2) store_tile(cur ^ 1);
    __syncthreads();
  }

  // ---- epilogue: reduce l across quads, normalize, bf16 store ----
  float s1 = l1;
  s1 += __shfl_xor(s1, 16);
  s1 += __shfl_xor(s1, 32);
  float s2 = l2;
  s2 += __shfl_xor(s2, 16);
  s2 += __shfl_xor(s2, 32);
  const float inv1 = 1.0f / s1;
  const float inv2 = 1.0f / s2;
  ushort_t* cb = ctx + (size_t)(b * L) * QCOLS + h * HD;
#pragma unroll
  for (int c = 0; c < 4; ++c) {
    uint_t w1[2], w2[2];
    w1[0] = pack2_bf16(o1[c][0] * inv1, o1[c][1] * inv1);
    w1[1] = pack2_bf16(o1[c][2] * inv1, o1[c][3] * inv1);
    w2[0] = pack2_bf16(o2[c][0] * inv2, o2[c][1] * inv2);
    w2[1] = pack2_bf16(o2[c][2] * inv2, o2[c][3] * inv2);
    *(uint2*)(cb + (size_t)(qrb1 + l15) * QCOLS + c * 16 + quad * 4) =
        *(uint2*)w1;
    *(uint2*)(cb + (size_t)(qrb2 + l15) * QCOLS + c * 16 + quad * 4) =
        *(uint2*)w2;
  }
}

// ---------------------------------------------------------------------------
extern "C" void kernel_launch(void* const* d_in, const int* in_sizes, int n_in,
                              void* d_out, int out_size, void* d_ws,
                              size_t ws_size, hipStream_t stream) {
  const float* x = (const float*)d_in[0];
  const float* cosp = (const float*)d_in[1];
  const float* sinp = (const float*)d_in[2];
  // d_in[3] = mask (unused)
  const float* wq = (const float*)d_in[4];
  const float* bq = (const float*)d_in[5];
  const float* wk = (const float*)d_in[6];
  const float* bk = (const float*)d_in[7];
  const float* wv = (const float*)d_in[8];
  const float* bv = (const float*)d_in[9];
  const float* wo = (const float*)d_in[10];
  float* out = (float*)d_out;

  char* ws = (char*)d_ws;
  ushort_t* qkvb = (ushort_t*)ws;  // [ROWS][QKVS] bf16, roped + q-scaled
  ws += (size_t)ROWS * QKVS * 2;
  short* xb = (short*)ws;
  ws += (size_t)ROWS * HID * 2;
  short* wqkvb = (short*)ws;
  ws += (size_t)QKVS * HID * 2;
  short* wob = (short*)ws;
  ws += (size_t)HID * QCOLS * 2;
  ushort_t* ctxb = (ushort_t*)ws;
  ws += (size_t)ROWS * QCOLS * 2;
  float* bqkv = (float*)ws;
  ws += QKVS * 4;

  {
    int n8 = ROWS * HID / 8;
    cast_bf16_kernel<<<(n8 + 255) / 256, 256, 0, stream>>>(x, xb, n8);
    int nq8 = QCOLS * HID / 8;
    cast_bf16_kernel<<<(nq8 + 255) / 256, 256, 0, stream>>>(wq, wqkvb, nq8);
    int nk8 = KCOLS * HID / 8;
    cast_bf16_kernel<<<(nk8 + 255) / 256, 256, 0, stream>>>(
        wk, wqkvb + (size_t)QCOLS * HID, nk8);
    cast_bf16_kernel<<<(nk8 + 255) / 256, 256, 0, stream>>>(
        wv, wqkvb + (size_t)(QCOLS + KCOLS) * HID, nk8);
    int no8 = HID * QCOLS / 8;
    cast_bf16_kernel<<<(no8 + 255) / 256, 256, 0, stream>>>(wo, wob, no8);
    pack_bias_kernel<<<(QKVS + 255) / 256, 256, 0, stream>>>(bq, bk, bv, bqkv);
  }

  // fused QKV projection + bias + RoPE + q-scale -> bf16 qkv
  gemm_bf16_kernel<true><<<dim3(QKVS / GTN, ROWS / GTM), 256, 0, stream>>>(
      xb, wqkvb, bqkv, nullptr, (short*)qkvb, cosp, sinp, ROWS, QKVS, HID);

  // attention -> bf16 ctx
  attn_mfma_kernel<<<dim3(L / (2 * BK), NH, B), 256, 0, stream>>>(qkvb, ctxb);

  // output projection -> fp32 out
  gemm_bf16_kernel<false><<<dim3(HID / GTN, ROWS / GTM), 256, 0, stream>>>(
      (const short*)ctxb, wob, nullptr, out, nullptr, nullptr, nullptr, ROWS,
      HID, QCOLS);
}

// Round 9
// 297.657 us; speedup vs baseline: 16.2999x; 1.0403x over previous
//
#include <hip/hip_runtime.h>
#include <hip/hip_bf16.h>
#include <math.h>

// Problem constants
#define B 4
#define L 2048
#define HID 896
#define NH 14
#define NKV 2
#define HD 64
#define GROUPS 7           // NH / NKV
#define QCOLS (NH * HD)    // 896
#define KCOLS (NKV * HD)   // 128
#define ROWS (B * L)       // 8192
#define QKVS 1152          // fused qkv row stride (896 q + 128 k + 128 v)

typedef __attribute__((ext_vector_type(8))) short bf16x8;
typedef __attribute__((ext_vector_type(4))) short bf16x4;
typedef __attribute__((ext_vector_type(4))) float f32x4;
typedef unsigned short ushort_t;
typedef unsigned int uint_t;

__device__ inline short f2bf(float f) {
  union { __hip_bfloat16 h; short s; } u;
  u.h = __float2bfloat16(f);
  return u.s;
}

__device__ inline uint_t pack2_bf16(float a, float b) {
  return (uint_t)(ushort_t)f2bf(a) | ((uint_t)(ushort_t)f2bf(b) << 16);
}

#if defined(__HIP_DEVICE_COMPILE__)
__device__ inline f32x4 mfma16(bf16x4 a, bf16x4 b, f32x4 c) {
  return __builtin_amdgcn_mfma_f32_16x16x16bf16_1k(a, b, c, 0, 0, 0);
}
#define EXP2(x) __builtin_amdgcn_exp2f(x)
#else
// host-pass stubs (never executed; keep the parser happy)
__device__ inline f32x4 mfma16(bf16x4 a, bf16x4 b, f32x4 c) { return c; }
#define EXP2(x) exp2f(x)
#endif

__device__ inline void gload_lds16(const void* g, void* l) {
  __builtin_amdgcn_global_load_lds(
      (const __attribute__((address_space(1))) unsigned int*)g,
      (__attribute__((address_space(3))) unsigned int*)l, 16, 0, 0);
}

// ---------------------------------------------------------------------------
// One merged prep kernel: bf16 casts of x/wq/wk/wv/wo + bias pack.
// ---------------------------------------------------------------------------
__device__ inline void cast8(const float* __restrict__ in,
                             short* __restrict__ out) {
  const float4* p = (const float4*)in;
  float4 a = p[0], b = p[1];
  short s[8];
  s[0] = f2bf(a.x); s[1] = f2bf(a.y); s[2] = f2bf(a.z); s[3] = f2bf(a.w);
  s[4] = f2bf(b.x); s[5] = f2bf(b.y); s[6] = f2bf(b.z); s[7] = f2bf(b.w);
  *(bf16x8*)out = *(bf16x8*)s;
}

#define NX8 (ROWS * HID / 8)    // 917504
#define NQ8 (QCOLS * HID / 8)   // 100352
#define NK8 (KCOLS * HID / 8)   // 14336
#define PREP_TOTAL (NX8 + NQ8 + NK8 + NK8 + NQ8 + QKVS)

__global__ void prep_kernel(const float* __restrict__ x,
                            const float* __restrict__ wq,
                            const float* __restrict__ wk,
                            const float* __restrict__ wv,
                            const float* __restrict__ wo,
                            const float* __restrict__ bq,
                            const float* __restrict__ bk,
                            const float* __restrict__ bv,
                            short* __restrict__ xb,
                            short* __restrict__ wqkvb,
                            short* __restrict__ wob,
                            float* __restrict__ bqkv) {
  int i = blockIdx.x * blockDim.x + threadIdx.x;
  if (i < NX8) { cast8(x + (size_t)i * 8, xb + (size_t)i * 8); return; }
  i -= NX8;
  if (i < NQ8) { cast8(wq + (size_t)i * 8, wqkvb + (size_t)i * 8); return; }
  i -= NQ8;
  if (i < NK8) {
    cast8(wk + (size_t)i * 8, wqkvb + (size_t)QCOLS * HID + (size_t)i * 8);
    return;
  }
  i -= NK8;
  if (i < NK8) {
    cast8(wv + (size_t)i * 8,
          wqkvb + (size_t)(QCOLS + KCOLS) * HID + (size_t)i * 8);
    return;
  }
  i -= NK8;
  if (i < NQ8) { cast8(wo + (size_t)i * 8, wob + (size_t)i * 8); return; }
  i -= NQ8;
  if (i < QKVS) {
    float v;
    if (i < QCOLS) v = bq[i];
    else if (i < QCOLS + KCOLS) v = bk[i - QCOLS];
    else v = bv[i - QCOLS - KCOLS];
    bqkv[i] = v;
  }
}

// ---------------------------------------------------------------------------
// bf16 MFMA GEMM: C[M,N] = A[M,K] @ W[N,K]^T (+ bias).
// ROPE=true: bf16 out with fused RoPE (+QSCALE on q heads); else fp32 out.
// Wave's 64 output cols = exactly one 64-wide head (tiles 128, heads 64).
// ---------------------------------------------------------------------------
#define GTM 128
#define GTN 128
#define GTK 32
#define QSCALE 0.18033688011112042f  // 0.125 * log2(e)

template <bool ROPE>
__global__ __launch_bounds__(256) void gemm_bf16_kernel(
    const short* __restrict__ A, const short* __restrict__ W,
    const float* __restrict__ bias, float* __restrict__ C,
    short* __restrict__ Cb, const float* __restrict__ cosp,
    const float* __restrict__ sinp, int M, int N, int K) {
  __shared__ short As[GTM * GTK];
  __shared__ short Bs[GTN * GTK];

  const int tid = threadIdx.x;
  const int wave = tid >> 6;
  const int lane = tid & 63;
  const int l15 = lane & 15;
  const int quad = lane >> 4;
  const int m0 = blockIdx.y * GTM;
  const int n0 = blockIdx.x * GTN;
  const int wm = (wave >> 1) * 64;
  const int wn = (wave & 1) * 64;

  f32x4 acc[4][4] = {};

  const int c0 = tid, c1 = tid + 256;
  const int r0 = c0 >> 2, ko0 = (c0 & 3) * 8;
  const int r1 = c1 >> 2, ko1 = (c1 & 3) * 8;
  const short* Ag0 = A + (size_t)(m0 + r0) * K + ko0;
  const short* Ag1 = A + (size_t)(m0 + r1) * K + ko1;
  const short* Wg0 = W + (size_t)(n0 + r0) * K + ko0;
  const short* Wg1 = W + (size_t)(n0 + r1) * K + ko1;

  for (int k0 = 0; k0 < K; k0 += GTK) {
    __syncthreads();
    gload_lds16(Ag0 + k0, As + c0 * 8);
    gload_lds16(Ag1 + k0, As + c1 * 8);
    gload_lds16(Wg0 + k0, Bs + c0 * 8);
    gload_lds16(Wg1 + k0, Bs + c1 * 8);
    __syncthreads();

    bf16x8 af[4], bfr[4];
#pragma unroll
    for (int i = 0; i < 4; ++i)
      af[i] = *(bf16x8*)(As + (wm + i * 16 + l15) * GTK + quad * 8);
#pragma unroll
    for (int j = 0; j < 4; ++j)
      bfr[j] = *(bf16x8*)(Bs + (wn + j * 16 + l15) * GTK + quad * 8);
#pragma unroll
    for (int i = 0; i < 4; ++i)
#pragma unroll
      for (int j = 0; j < 4; ++j)
        acc[i][j] = __builtin_amdgcn_mfma_f32_16x16x32_bf16(af[i], bfr[j],
                                                            acc[i][j], 0, 0, 0);
  }

  const int col0 = n0 + wn + l15;
  if (ROPE) {
    const int hw = (n0 + wn) >> 6;  // head index within qkv row
    float bv[4];
#pragma unroll
    for (int j = 0; j < 4; ++j) bv[j] = bias[col0 + 16 * j];
    if (hw < NH + NKV) {
      // q/k head: rope pairs (d, d+32) = (j, j+2) in-register
      const float sc = (hw < NH) ? QSCALE : 1.0f;
#pragma unroll
      for (int i = 0; i < 4; ++i) {
        const int rowb = m0 + wm + i * 16 + quad * 4;
#pragma unroll
        for (int r = 0; r < 4; ++r) {
          const int row = rowb + r;
          const int l = row & (L - 1);
          const float* cp = cosp + l * HD + l15;
          const float* sp = sinp + l * HD + l15;
#pragma unroll
          for (int j = 0; j < 2; ++j) {
            const float cv = cp[16 * j];
            const float sv = sp[16 * j];
            const float a = acc[i][j][r] + bv[j];
            const float b2 = acc[i][j + 2][r] + bv[j + 2];
            Cb[(size_t)row * N + col0 + 16 * j] = f2bf((a * cv - b2 * sv) * sc);
            Cb[(size_t)row * N + col0 + 16 * j + 32] =
                f2bf((b2 * cv + a * sv) * sc);
          }
        }
      }
    } else {
      // v head: plain bias + bf16 store
#pragma unroll
      for (int j = 0; j < 4; ++j)
#pragma unroll
        for (int i = 0; i < 4; ++i) {
          const int rowb = m0 + wm + i * 16 + quad * 4;
#pragma unroll
          for (int r = 0; r < 4; ++r)
            Cb[(size_t)(rowb + r) * N + col0 + 16 * j] =
                f2bf(acc[i][j][r] + bv[j]);
        }
    }
  } else {
#pragma unroll
    for (int j = 0; j < 4; ++j) {
      const int col = col0 + 16 * j;
      const float bv = bias ? bias[col] : 0.f;
#pragma unroll
      for (int i = 0; i < 4; ++i) {
        const int rowb = m0 + wm + i * 16 + quad * 4;
#pragma unroll
        for (int r = 0; r < 4; ++r)
          C[(size_t)(rowb + r) * N + col] = acc[i][j][r] + bv;
      }
    }
  }
}

// ---------------------------------------------------------------------------
// Flash attention, S^T formulation, BK=64 key tiles, ONE 64-row q-strip per
// block (4 waves x 16 q rows). Grid (32,14,4)=1792 blocks -> backfill keeps
// CUs saturated; longest strips dispatch first.
//   S^T[key][q] = mfma_16x16x32(A=K, B=Q)  (C: col=q=l15, row=key=quad*4+r)
//   C-layout == A/B-layout of mfma_16x16x16 -> PV with zero LDS round-trip:
//   O^T[d][q] += mfma_16x16x16(A=V^T-frag, B=P^T-frag).
// K tile: XOR-swizzled (8-short granule) -> conflict-free b128 r/w.
// V^T tile: VSTR=70 (odd-dword stride) -> 2-way (free) b16 writes/b32 reads.
// ---------------------------------------------------------------------------
#define BK 64
#define VSTR 70

__global__ __launch_bounds__(256, 4) void attn_mfma_kernel(
    const ushort_t* __restrict__ qkv, ushort_t* __restrict__ ctx) {
  const int strip = (L / BK - 1) - blockIdx.x;  // longest first
  const int h = blockIdx.y;
  const int b = blockIdx.z;
  const int kvh = h / GROUPS;
  const int tid = threadIdx.x;
  const int wave = tid >> 6;
  const int lane = tid & 63;
  const int l15 = lane & 15;
  const int quad = lane >> 4;

  const int lt = strip;  // last tile index
  const int qrb = strip * BK + wave * 16;

  __shared__ short Kt[2][BK * 64];
  __shared__ short Vt[2][HD * VSTR];

  // Q fragments (QSCALE pre-folded by projection kernel)
  bf16x8 qf[2];
  {
    const ushort_t* qp = qkv + (size_t)(b * L + qrb + l15) * QKVS + h * HD;
    qf[0] = *(const bf16x8*)(qp + quad * 8);
    qf[1] = *(const bf16x8*)(qp + 32 + quad * 8);
  }

  float m = -INFINITY, lsum = 0.f;
  f32x4 o[4] = {};  // O^T: o[c][r] = O[q=l15][d=c*16+quad*4+r]

  const ushort_t* kb = qkv + (size_t)(b * L) * QKVS + QCOLS + kvh * HD;
  const ushort_t* vb = kb + KCOLS;

  // staging assignments
  const int skey = tid >> 2;            // K: key row 0..63
  const int sblk = (tid & 3) * 2;       // K: first 8-d block
  const int ksw0 = (sblk ^ (skey & 7)) * 8;
  const int ksw1 = ((sblk + 1) ^ (skey & 7)) * 8;
  const int vd = tid & 63;              // V: d
  const int vk0 = wave * 16;            // V: key band base (wave-uniform)

  uint4 kr0, kr1;
  ushort_t vr[16];

  auto load_tile = [&](int j0) {
    const ushort_t* kp = kb + (size_t)(j0 + skey) * QKVS + sblk * 8;
    kr0 = *(const uint4*)(kp);
    kr1 = *(const uint4*)(kp + 8);
    const ushort_t* vp = vb + (size_t)(j0 + vk0) * QKVS + vd;
#pragma unroll
    for (int s = 0; s < 16; ++s) vr[s] = vp[(size_t)s * QKVS];
  };
  auto store_tile = [&](int bufi) {
    *(uint4*)(&Kt[bufi][skey * 64 + ksw0]) = kr0;
    *(uint4*)(&Kt[bufi][skey * 64 + ksw1]) = kr1;
#pragma unroll
    for (int s = 0; s < 16; ++s) Vt[bufi][vd * VSTR + vk0 + s] = (short)vr[s];
  };

  load_tile(0);
  store_tile(0);
  __syncthreads();

  for (int t = 0; t <= lt; ++t) {
    const int j0 = t * BK;
    const int cur = t & 1;
    if (t < lt) load_tile(j0 + BK);

    const short* Kb = Kt[cur];
    const short* Vb = Vt[cur];

    // ---- S^T = K Q^T (4 key-subtiles x 2 d-halves) ----
    f32x4 St[4];
#pragma unroll
    for (int tt = 0; tt < 4; ++tt) {
      const int key = tt * 16 + l15;
      const short* krow = Kb + key * 64;
      bf16x8 k0 = *(const bf16x8*)(krow + (quad ^ (key & 7)) * 8);
      bf16x8 k1 = *(const bf16x8*)(krow + ((4 + quad) ^ (key & 7)) * 8);
      f32x4 a = {};
      a = __builtin_amdgcn_mfma_f32_16x16x32_bf16(k0, qf[0], a, 0, 0, 0);
      a = __builtin_amdgcn_mfma_f32_16x16x32_bf16(k1, qf[1], a, 0, 0, 0);
      St[tt] = a;
    }

    // ---- causal mask + online softmax (local-max exp trick) ----
    const int limq = (t == lt) ? (qrb + l15 - j0 - quad * 4) : 63;
    float s[16];
#pragma unroll
    for (int tt = 0; tt < 4; ++tt)
#pragma unroll
      for (int r = 0; r < 4; ++r)
        s[tt * 4 + r] = (tt * 16 + r <= limq) ? St[tt][r] : -1e30f;
    float mt = fmaxf(s[0], s[1]);
#pragma unroll
    for (int i = 2; i < 16; ++i) mt = fmaxf(mt, s[i]);
    float pl[16], psl = 0.f;
#pragma unroll
    for (int i = 0; i < 16; ++i) {
      pl[i] = EXP2(s[i] - mt);
      psl += pl[i];
    }
    float mg = fmaxf(mt, __shfl_xor(mt, 16));
    mg = fmaxf(mg, __shfl_xor(mg, 32));
    const float mn = fmaxf(m, mg);
    const float f = EXP2(mt - mn);
    const float al = EXP2(m - mn);
    m = mn;
    lsum = lsum * al + psl * f;
#pragma unroll
    for (int c = 0; c < 4; ++c)
#pragma unroll
      for (int r = 0; r < 4; ++r) o[c][r] *= al;
    uint_t pk[8];
#pragma unroll
    for (int tt = 0; tt < 4; ++tt) {
      pk[2 * tt] = pack2_bf16(pl[4 * tt] * f, pl[4 * tt + 1] * f);
      pk[2 * tt + 1] = pack2_bf16(pl[4 * tt + 2] * f, pl[4 * tt + 3] * f);
    }

    // ---- PV: O^T += V^T P^T ----
#pragma unroll
    for (int c = 0; c < 4; ++c) {
      const short* vrow = Vb + (c * 16 + l15) * VSTR + quad * 4;
#pragma unroll
      for (int tt = 0; tt < 4; ++tt) {
        union { bf16x4 v; uint_t u[2]; } vfu;
        vfu.u[0] = *(const uint_t*)(vrow + tt * 16);
        vfu.u[1] = *(const uint_t*)(vrow + tt * 16 + 2);
        union { bf16x4 v; uint_t u[2]; } pa;
        pa.u[0] = pk[2 * tt];
        pa.u[1] = pk[2 * tt + 1];
        o[c] = mfma16(vfu.v, pa.v, o[c]);
      }
    }

    if (t < lt) store_tile(cur ^ 1);
    __syncthreads();
  }

  // ---- epilogue: reduce l across quads, normalize, bf16 store ----
  float s1 = lsum;
  s1 += __shfl_xor(s1, 16);
  s1 += __shfl_xor(s1, 32);
  const float inv = 1.0f / s1;
  ushort_t* cb = ctx + (size_t)(b * L) * QCOLS + h * HD;
#pragma unroll
  for (int c = 0; c < 4; ++c) {
    uint_t w[2];
    w[0] = pack2_bf16(o[c][0] * inv, o[c][1] * inv);
    w[1] = pack2_bf16(o[c][2] * inv, o[c][3] * inv);
    *(uint2*)(cb + (size_t)(qrb + l15) * QCOLS + c * 16 + quad * 4) =
        *(uint2*)w;
  }
}

// ---------------------------------------------------------------------------
extern "C" void kernel_launch(void* const* d_in, const int* in_sizes, int n_in,
                              void* d_out, int out_size, void* d_ws,
                              size_t ws_size, hipStream_t stream) {
  const float* x = (const float*)d_in[0];
  const float* cosp = (const float*)d_in[1];
  const float* sinp = (const float*)d_in[2];
  // d_in[3] = mask (unused)
  const float* wq = (const float*)d_in[4];
  const float* bq = (const float*)d_in[5];
  const float* wk = (const float*)d_in[6];
  const float* bk = (const float*)d_in[7];
  const float* wv = (const float*)d_in[8];
  const float* bv = (const float*)d_in[9];
  const float* wo = (const float*)d_in[10];
  float* out = (float*)d_out;

  char* ws = (char*)d_ws;
  ushort_t* qkvb = (ushort_t*)ws;  // [ROWS][QKVS] bf16, roped + q-scaled
  ws += (size_t)ROWS * QKVS * 2;
  short* xb = (short*)ws;
  ws += (size_t)ROWS * HID * 2;
  short* wqkvb = (short*)ws;
  ws += (size_t)QKVS * HID * 2;
  short* wob = (short*)ws;
  ws += (size_t)HID * QCOLS * 2;
  ushort_t* ctxb = (ushort_t*)ws;
  ws += (size_t)ROWS * QCOLS * 2;
  float* bqkv = (float*)ws;
  ws += QKVS * 4;

  // merged prep: casts + bias pack
  prep_kernel<<<(PREP_TOTAL + 255) / 256, 256, 0, stream>>>(
      x, wq, wk, wv, wo, bq, bk, bv, xb, wqkvb, wob, bqkv);

  // fused QKV projection + bias + RoPE + q-scale -> bf16 qkv
  gemm_bf16_kernel<true><<<dim3(QKVS / GTN, ROWS / GTM), 256, 0, stream>>>(
      xb, wqkvb, bqkv, nullptr, (short*)qkvb, cosp, sinp, ROWS, QKVS, HID);

  // attention -> bf16 ctx
  attn_mfma_kernel<<<dim3(L / BK, NH, B), 256, 0, stream>>>(qkvb, ctxb);

  // output projection -> fp32 out
  gemm_bf16_kernel<false><<<dim3(HID / GTN, ROWS / GTM), 256, 0, stream>>>(
      (const short*)ctxb, wob, nullptr, out, nullptr, nullptr, nullptr, ROWS,
      HID, QCOLS);
}